// Round 2
// baseline (4047.241 us; speedup 1.0000x reference)
//
#include <hip/hip_runtime.h>
#include <hip/hip_bf16.h>
#include <utility>

// Shapes: b=4, n=8192, d=512, h=8, dh=64, m=256 landmarks, l=32, conv k=33. bh=32.
// bf16 storage for big tensors (q/k/v/T/U/outh), fp32 accumulation everywhere,
// fp32 for the pinv path (Newton-Schulz amplifies input perturbations ~1000x).

typedef unsigned short ushort_t;

__device__ inline float bf2f(ushort_t u) {
  union { unsigned int i; float f; } x; x.i = ((unsigned int)u) << 16; return x.f;
}
__device__ inline ushort_t f2bf(float f) {
  union { float f; unsigned int i; } x; x.f = f;
  unsigned int r = x.i + 0x7FFF + ((x.i >> 16) & 1);   // round-nearest-even
  return (ushort_t)(r >> 16);
}

// ---------------- LN stats: mu/rstd per row (512 elems) ----------------
__global__ __launch_bounds__(256) void ln_stats(const float* __restrict__ x,
                                                float* __restrict__ mu,
                                                float* __restrict__ rstd) {
  int row = blockIdx.x; int t = threadIdx.x;
  const float* xr = x + (size_t)row * 512;
  float v0 = xr[t], v1 = xr[t + 256];
  __shared__ float rs[256], rq[256];
  rs[t] = v0 + v1; rq[t] = v0 * v0 + v1 * v1;
  __syncthreads();
  for (int off = 128; off > 0; off >>= 1) {
    if (t < off) { rs[t] += rs[t + off]; rq[t] += rq[t + off]; }
    __syncthreads();
  }
  if (t == 0) {
    float m = rs[0] * (1.f / 512.f);
    float var = rq[0] * (1.f / 512.f) - m * m;
    mu[row] = m;
    rstd[row] = rsqrtf(var + 1e-5f);
  }
}

// ------- QKV GEMM with fused LN: [32768,512]@[512,1536] -> q/k/v bf16 -------
__global__ __launch_bounds__(256) void qkv_gemm(const float* __restrict__ x,
                                                const float* __restrict__ mu,
                                                const float* __restrict__ rstd,
                                                const float* __restrict__ g,
                                                const float* __restrict__ be,
                                                const float* __restrict__ Bw,
                                                ushort_t* __restrict__ q,
                                                ushort_t* __restrict__ k,
                                                ushort_t* __restrict__ v) {
  int bn0 = blockIdx.x * 64, bm0 = blockIdx.y * 64;
  __shared__ float As[32][65];
  __shared__ float Bs[32][65];
  int t = threadIdx.x, tm = t >> 4, tn = t & 15;
  float acc[16];
#pragma unroll
  for (int i = 0; i < 16; i++) acc[i] = 0.f;
  for (int k0 = 0; k0 < 512; k0 += 32) {
#pragma unroll
    for (int i = 0; i < 8; i++) {
      int idx = t + (i << 8); int r = idx >> 5, c = idx & 31;
      int gm = bm0 + r, kk = k0 + c;
      As[c][r] = (x[(size_t)gm * 512 + kk] - mu[gm]) * rstd[gm] * g[kk] + be[kk];
    }
#pragma unroll
    for (int i = 0; i < 8; i++) {
      int idx = t + (i << 8); int r = idx >> 6, c = idx & 63;
      Bs[r][c] = Bw[(size_t)(k0 + r) * 1536 + bn0 + c];
    }
    __syncthreads();
#pragma unroll
    for (int kk = 0; kk < 32; kk++) {
      float a[4], b[4];
#pragma unroll
      for (int i = 0; i < 4; i++) { a[i] = As[kk][tm * 4 + i]; b[i] = Bs[kk][tn * 4 + i]; }
#pragma unroll
      for (int i = 0; i < 4; i++)
#pragma unroll
        for (int j = 0; j < 4; j++) acc[i * 4 + j] = fmaf(a[i], b[j], acc[i * 4 + j]);
    }
    __syncthreads();
  }
#pragma unroll
  for (int i = 0; i < 4; i++)
#pragma unroll
    for (int j = 0; j < 4; j++) {
      int gm = bm0 + tm * 4 + i, gn = bn0 + tn * 4 + j;
      int part = gn >> 9, head = (gn >> 6) & 7, d = gn & 63;
      size_t dst = ((size_t)((gm >> 13) * 8 + head) * 8192 + (gm & 8191)) * 64 + d;
      float val = acc[i * 4 + j];
      if (part == 0) q[dst] = f2bf(val * 0.125f);
      else if (part == 1) k[dst] = f2bf(val);
      else v[dst] = f2bf(val);
    }
}

// --------- landmarks: mean over 32 rows; fp32 (for sim2) + bf16 copies ------
__global__ void land_kernel(const ushort_t* __restrict__ q, const ushort_t* __restrict__ k,
                            float* __restrict__ qlf, float* __restrict__ klf,
                            ushort_t* __restrict__ qlh, ushort_t* __restrict__ klh) {
  int bh = blockIdx.y, mi = blockIdx.x, d = threadIdx.x;  // 64 threads
  size_t base = ((size_t)bh * 8192 + (size_t)mi * 32) * 64 + d;
  float sq = 0.f, sk = 0.f;
  for (int j = 0; j < 32; j++) {
    sq += bf2f(q[base + (size_t)j * 64]);
    sk += bf2f(k[base + (size_t)j * 64]);
  }
  size_t o = ((size_t)bh * 256 + mi) * 64 + d;
  float aq = sq * (1.f / 32.f), ak = sk * (1.f / 32.f);
  qlf[o] = aq; klf[o] = ak;
  qlh[o] = f2bf(aq); klh[o] = f2bf(ak);
}

// ------------- sim2 + softmax -> attn2 [32][256][256] fp32 -----------------
__global__ __launch_bounds__(256) void sim2_kernel(const float* __restrict__ ql,
                                                   const float* __restrict__ kl,
                                                   float* __restrict__ attn2) {
  int bh = blockIdx.y, row = blockIdx.x, t = threadIdx.x;
  __shared__ float qrow[64];
  __shared__ float red[256];
  if (t < 64) qrow[t] = ql[((size_t)bh * 256 + row) * 64 + t];
  __syncthreads();
  const float* kr = kl + ((size_t)bh * 256 + t) * 64;
  float s = 0.f;
#pragma unroll
  for (int kd = 0; kd < 64; kd++) s = fmaf(qrow[kd], kr[kd], s);
  red[t] = s; __syncthreads();
  for (int off = 128; off > 0; off >>= 1) { if (t < off) red[t] = fmaxf(red[t], red[t + off]); __syncthreads(); }
  float mx = red[0]; __syncthreads();
  float pv = __expf(s - mx);
  red[t] = pv; __syncthreads();
  for (int off = 128; off > 0; off >>= 1) { if (t < off) red[t] += red[t + off]; __syncthreads(); }
  float inv = 1.f / red[0];
  attn2[((size_t)bh * 256 + row) * 256 + t] = pv * inv;
}

// ------------- pinv init helpers (fp32) ------------------------------------
__global__ __launch_bounds__(256) void abssum_kernel(const float* __restrict__ x,
                                                     float* __restrict__ rowsum,
                                                     float* __restrict__ colsum) {
  int bh = blockIdx.x, t = threadIdx.x;
  const float* xb = x + ((size_t)bh << 16);
  float s = 0.f;
  for (int c = 0; c < 256; c++) s += fabsf(xb[(size_t)t * 256 + c]);
  rowsum[bh * 256 + t] = s;
  float s2 = 0.f;
  for (int r = 0; r < 256; r++) s2 += fabsf(xb[(size_t)r * 256 + t]);
  colsum[bh * 256 + t] = s2;
}

__global__ __launch_bounds__(256) void pinv_scale_kernel(const float* __restrict__ rowsum,
                                                         const float* __restrict__ colsum,
                                                         float* __restrict__ scl) {
  int t = threadIdx.x;
  float m1 = 0.f, m2 = 0.f;
  for (int i = t; i < 8192; i += 256) { m1 = fmaxf(m1, rowsum[i]); m2 = fmaxf(m2, colsum[i]); }
  __shared__ float r1[256], r2[256];
  r1[t] = m1; r2[t] = m2; __syncthreads();
  for (int off = 128; off > 0; off >>= 1) {
    if (t < off) { r1[t] = fmaxf(r1[t], r1[t + off]); r2[t] = fmaxf(r2[t], r2[t + off]); }
    __syncthreads();
  }
  if (t == 0) scl[0] = 1.f / (r1[0] * r2[0]);
}

__global__ __launch_bounds__(256) void zinit_kernel(const float* __restrict__ x,
                                                    const float* __restrict__ scl,
                                                    float* __restrict__ z) {
  int bh = blockIdx.y, i = blockIdx.x, j = threadIdx.x;
  float s = scl[0];
  z[((size_t)bh << 16) + (size_t)i * 256 + j] = x[((size_t)bh << 16) + (size_t)j * 256 + i] * s;
}

// ------------- batched 256x256 GEMM: C = diagc*I + alpha*(A@B), fp32 --------
__global__ __launch_bounds__(256) void bmm256_kernel(const float* __restrict__ A,
                                                     const float* __restrict__ B,
                                                     float* __restrict__ C,
                                                     float alpha, float diagc) {
  int bh = blockIdx.y, tile = blockIdx.x;
  int bm0 = (tile >> 2) << 6, bn0 = (tile & 3) << 6;
  const float* Ab = A + ((size_t)bh << 16);
  const float* Bb = B + ((size_t)bh << 16);
  float* Cb = C + ((size_t)bh << 16);
  __shared__ float As[32][65];
  __shared__ float Bs[32][65];
  int t = threadIdx.x, tm = t >> 4, tn = t & 15;
  float acc[16];
#pragma unroll
  for (int i = 0; i < 16; i++) acc[i] = 0.f;
  for (int k0 = 0; k0 < 256; k0 += 32) {
#pragma unroll
    for (int i = 0; i < 8; i++) {
      int idx = t + (i << 8); int r = idx >> 5, c = idx & 31;
      As[c][r] = Ab[(size_t)(bm0 + r) * 256 + k0 + c];
    }
#pragma unroll
    for (int i = 0; i < 8; i++) {
      int idx = t + (i << 8); int r = idx >> 6, c = idx & 63;
      Bs[r][c] = Bb[(size_t)(k0 + r) * 256 + bn0 + c];
    }
    __syncthreads();
#pragma unroll
    for (int kk = 0; kk < 32; kk++) {
      float a[4], b[4];
#pragma unroll
      for (int i = 0; i < 4; i++) { a[i] = As[kk][tm * 4 + i]; b[i] = Bs[kk][tn * 4 + i]; }
#pragma unroll
      for (int i = 0; i < 4; i++)
#pragma unroll
        for (int j = 0; j < 4; j++) acc[i * 4 + j] = fmaf(a[i], b[j], acc[i * 4 + j]);
    }
    __syncthreads();
  }
#pragma unroll
  for (int i = 0; i < 4; i++)
#pragma unroll
    for (int j = 0; j < 4; j++) {
      int gm = bm0 + tm * 4 + i, gn = bn0 + tn * 4 + j;
      Cb[(size_t)gm * 256 + gn] = alpha * acc[i * 4 + j] + (gm == gn ? diagc : 0.f);
    }
}

__global__ __launch_bounds__(256) void iminus_kernel(const float* __restrict__ A,
                                                     float* __restrict__ G, float c0) {
  size_t idx = (size_t)blockIdx.x * 256 + threadIdx.x;
  int r = (int)((idx >> 8) & 255), c = (int)(idx & 255);
  G[idx] = (r == c ? c0 : 0.f) - A[idx];
}

// ------------- fused flash (all bf16 in, bf16 out, fp32 math) ---------------
// out = softmax(qsrc @ ksrc^T) @ vsrc. qsrc [bh][nq][64]; ksrc/vsrc [bh][nkv][64].
__global__ __launch_bounds__(256) void flash_kernel(const ushort_t* __restrict__ qsrc,
                                                    const ushort_t* __restrict__ ksrc,
                                                    const ushort_t* __restrict__ vsrc,
                                                    ushort_t* __restrict__ out,
                                                    int nq, int nkv) {
  int bh = blockIdx.y;
  int q0 = blockIdx.x * 32;
  int t = threadIdx.x, rg = t >> 3, sl = t & 7;
  __shared__ float qs[32 * 68];
  __shared__ float ks[64 * 68];
  __shared__ float vs[64 * 64];
  __shared__ float ps[32 * 65];
  {
    int r = t >> 3, c8 = (t & 7) << 3;   // 2048 elems = 256 chunks of 8 bf16
    uint4 u = *(const uint4*)(qsrc + ((size_t)bh * nq + q0 + r) * 64 + c8);
    const ushort_t* s = (const ushort_t*)&u;
#pragma unroll
    for (int j = 0; j < 8; j++) qs[r * 68 + c8 + j] = bf2f(s[j]);
  }
  __syncthreads();
  float4 qreg[16];
#pragma unroll
  for (int i = 0; i < 16; i++) qreg[i] = *(const float4*)&qs[rg * 68 + i * 4];
  float acc[8];
#pragma unroll
  for (int i = 0; i < 8; i++) acc[i] = 0.f;
  float mrun = -1e30f, lrun = 0.f;
  for (int n0 = 0; n0 < nkv; n0 += 64) {
    __syncthreads();
    for (int i = t; i < 512; i += 256) {   // 4096 elems = 512 chunks of 8
      int r = i >> 3, c8 = (i & 7) << 3;
      uint4 uk = *(const uint4*)(ksrc + ((size_t)bh * nkv + n0 + r) * 64 + c8);
      uint4 uv = *(const uint4*)(vsrc + ((size_t)bh * nkv + n0 + r) * 64 + c8);
      const ushort_t* sk = (const ushort_t*)&uk;
      const ushort_t* sv = (const ushort_t*)&uv;
#pragma unroll
      for (int j = 0; j < 8; j++) {
        ks[r * 68 + c8 + j] = bf2f(sk[j]);
        vs[r * 64 + c8 + j] = bf2f(sv[j]);
      }
    }
    __syncthreads();
    float sc[8]; float tmax = -1e30f;
#pragma unroll
    for (int jj = 0; jj < 8; jj++) {
      int c = sl + (jj << 3);
      const float4* krow = (const float4*)&ks[c * 68];
      float s = 0.f;
#pragma unroll
      for (int i = 0; i < 16; i++) {
        float4 kv = krow[i], qv = qreg[i];
        s += qv.x * kv.x + qv.y * kv.y + qv.z * kv.z + qv.w * kv.w;
      }
      sc[jj] = s; tmax = fmaxf(tmax, s);
    }
#pragma unroll
    for (int off = 1; off < 8; off <<= 1) tmax = fmaxf(tmax, __shfl_xor(tmax, off));
    float mnew = fmaxf(mrun, tmax);
    float scalef = __expf(mrun - mnew);
    float tsum = 0.f;
#pragma unroll
    for (int jj = 0; jj < 8; jj++) {
      float pp = __expf(sc[jj] - mnew);
      ps[rg * 65 + sl + (jj << 3)] = pp;
      tsum += pp;
    }
#pragma unroll
    for (int off = 1; off < 8; off <<= 1) tsum += __shfl_xor(tsum, off);
    lrun = lrun * scalef + tsum;
    mrun = mnew;
    __syncthreads();
#pragma unroll
    for (int dd = 0; dd < 8; dd++) acc[dd] *= scalef;
    const int dbase = sl << 3;
    for (int c = 0; c < 64; c++) {
      float pp = ps[rg * 65 + c];
      const float4* vr = (const float4*)&vs[c * 64 + dbase];
      float4 v0 = vr[0], v1 = vr[1];
      acc[0] = fmaf(pp, v0.x, acc[0]); acc[1] = fmaf(pp, v0.y, acc[1]);
      acc[2] = fmaf(pp, v0.z, acc[2]); acc[3] = fmaf(pp, v0.w, acc[3]);
      acc[4] = fmaf(pp, v1.x, acc[4]); acc[5] = fmaf(pp, v1.y, acc[5]);
      acc[6] = fmaf(pp, v1.z, acc[6]); acc[7] = fmaf(pp, v1.w, acc[7]);
    }
  }
  float invl = 1.f / lrun;
  union { ushort_t s[8]; uint4 u; } ob;
#pragma unroll
  for (int j = 0; j < 8; j++) ob.s[j] = f2bf(acc[j] * invl);
  *(uint4*)(out + ((size_t)bh * nq + q0 + rg) * 64 + (sl << 3)) = ob.u;
}

// ------------- U = z @ T  (z fp32 [256,256], T bf16 [256,64]) ---------------
__global__ void zu_kernel(const float* __restrict__ z, const ushort_t* __restrict__ T,
                          ushort_t* __restrict__ U) {
  int bh = blockIdx.y, r = blockIdx.x, d = threadIdx.x;  // 64 threads
  const float* zr = z + ((size_t)bh << 16) + ((size_t)r << 8);
  float s = 0.f;
  for (int c = 0; c < 256; c++) s = fmaf(zr[c], bf2f(T[((size_t)bh * 256 + c) * 64 + d]), s);
  U[((size_t)bh * 256 + r) * 64 + d] = f2bf(s);
}

// ------------- depthwise residual conv over n (k=33), adds into outh -------
__global__ __launch_bounds__(256) void conv_kernel(const ushort_t* __restrict__ v,
                                                   const float* __restrict__ w,
                                                   ushort_t* __restrict__ outh) {
  int bh = blockIdx.y;
  int nr = blockIdx.x * 4 + (threadIdx.x >> 6);
  int d = threadIdx.x & 63, h = bh & 7;
  float s = 0.f;
#pragma unroll
  for (int kk = 0; kk < 33; kk++) {
    int nn = nr + kk - 16;
    if (nn >= 0 && nn < 8192)
      s = fmaf(w[h * 33 + kk], bf2f(v[((size_t)bh * 8192 + nn) * 64 + d]), s);
  }
  size_t o = ((size_t)bh * 8192 + nr) * 64 + d;
  outh[o] = f2bf(bf2f(outh[o]) + s);
}

// ------------- out proj: d_out = x + gather(outh) @ w_out + b_out ----------
__global__ __launch_bounds__(256) void out_gemm(const ushort_t* __restrict__ outh,
                                                const float* __restrict__ Bw,
                                                const float* __restrict__ x,
                                                const float* __restrict__ bo,
                                                float* __restrict__ out) {
  int bn0 = blockIdx.x * 64, bm0 = blockIdx.y * 64;
  __shared__ float As[32][65];
  __shared__ float Bs[32][65];
  int t = threadIdx.x, tm = t >> 4, tn = t & 15;
  float acc[16];
#pragma unroll
  for (int i = 0; i < 16; i++) acc[i] = 0.f;
  for (int k0 = 0; k0 < 512; k0 += 32) {
#pragma unroll
    for (int i = 0; i < 8; i++) {
      int idx = t + (i << 8); int r = idx >> 5, c = idx & 31;
      int gm = bm0 + r, kk = k0 + c;
      As[c][r] = bf2f(outh[((size_t)((gm >> 13) * 8 + (kk >> 6)) * 8192 + (gm & 8191)) * 64 + (kk & 63)]);
    }
#pragma unroll
    for (int i = 0; i < 8; i++) {
      int idx = t + (i << 8); int r = idx >> 6, c = idx & 63;
      Bs[r][c] = Bw[(size_t)(k0 + r) * 512 + bn0 + c];
    }
    __syncthreads();
#pragma unroll
    for (int kk = 0; kk < 32; kk++) {
      float a[4], b[4];
#pragma unroll
      for (int i = 0; i < 4; i++) { a[i] = As[kk][tm * 4 + i]; b[i] = Bs[kk][tn * 4 + i]; }
#pragma unroll
      for (int i = 0; i < 4; i++)
#pragma unroll
        for (int j = 0; j < 4; j++) acc[i * 4 + j] = fmaf(a[i], b[j], acc[i * 4 + j]);
    }
    __syncthreads();
  }
#pragma unroll
  for (int i = 0; i < 4; i++)
#pragma unroll
    for (int j = 0; j < 4; j++) {
      int gm = bm0 + tm * 4 + i, gn = bn0 + tn * 4 + j;
      size_t o = (size_t)gm * 512 + gn;
      out[o] = x[o] + bo[gn] + acc[i * 4 + j];
    }
}

extern "C" void kernel_launch(void* const* d_in, const int* in_sizes, int n_in,
                              void* d_out, int out_size, void* d_ws, size_t ws_size,
                              hipStream_t stream) {
  (void)in_sizes; (void)n_in; (void)out_size; (void)ws_size;
  const float* x     = (const float*)d_in[0];
  const float* g     = (const float*)d_in[1];
  const float* be    = (const float*)d_in[2];
  const float* wqkv  = (const float*)d_in[3];
  const float* wout  = (const float*)d_in[4];
  const float* bout  = (const float*)d_in[5];
  const float* convw = (const float*)d_in[6];
  float* out = (float*)d_out;

  char* base = (char*)d_ws;
  size_t off = 0;
  auto alloc = [&](size_t bytes) -> void* {
    void* r = base + off; off = (off + bytes + 255) & ~(size_t)255; return r;
  };
  const size_t NBH = (size_t)32 * 8192 * 64;   // 16.78M elems
  float*    mu    = (float*)alloc(32768 * 4);
  float*    rstd  = (float*)alloc(32768 * 4);
  ushort_t* q     = (ushort_t*)alloc(NBH * 2);
  ushort_t* k     = (ushort_t*)alloc(NBH * 2);
  ushort_t* v     = (ushort_t*)alloc(NBH * 2);
  ushort_t* outh  = (ushort_t*)alloc(NBH * 2);
  float*    qlf   = (float*)alloc((size_t)32 * 256 * 64 * 4);
  float*    klf   = (float*)alloc((size_t)32 * 256 * 64 * 4);
  ushort_t* qlh   = (ushort_t*)alloc((size_t)32 * 256 * 64 * 2);
  ushort_t* klh   = (ushort_t*)alloc((size_t)32 * 256 * 64 * 2);
  float*    attn2 = (float*)alloc((size_t)32 * 256 * 256 * 4);
  float*    z0    = (float*)alloc((size_t)32 * 256 * 256 * 4);
  float*    b1    = (float*)alloc((size_t)32 * 256 * 256 * 4);
  float*    b2    = (float*)alloc((size_t)32 * 256 * 256 * 4);
  float*    b3    = (float*)alloc((size_t)32 * 256 * 256 * 4);
  float*    rowsum = (float*)alloc(8192 * 4);
  float*    colsum = (float*)alloc(8192 * 4);
  float*    scl   = (float*)alloc(64);
  ushort_t* T     = (ushort_t*)alloc((size_t)32 * 256 * 64 * 2);
  ushort_t* U     = (ushort_t*)alloc((size_t)32 * 256 * 64 * 2);
  // total ~185 MB

  ln_stats<<<32768, 256, 0, stream>>>(x, mu, rstd);
  qkv_gemm<<<dim3(24, 512), 256, 0, stream>>>(x, mu, rstd, g, be, wqkv, q, k, v);
  land_kernel<<<dim3(256, 32), 64, 0, stream>>>(q, k, qlf, klf, qlh, klh);
  sim2_kernel<<<dim3(256, 32), 256, 0, stream>>>(qlf, klf, attn2);
  abssum_kernel<<<32, 256, 0, stream>>>(attn2, rowsum, colsum);
  pinv_scale_kernel<<<1, 256, 0, stream>>>(rowsum, colsum, scl);
  zinit_kernel<<<dim3(256, 32), 256, 0, stream>>>(attn2, scl, z0);

  float* pz = z0; float* pA = b1; float* pB = b2; float* pD = b3;
  for (int it = 0; it < 6; it++) {
    bmm256_kernel<<<dim3(16, 32), 256, 0, stream>>>(attn2, pz, pA, 1.f, 0.f);
    iminus_kernel<<<8192, 256, 0, stream>>>(pA, pB, 7.f);
    bmm256_kernel<<<dim3(16, 32), 256, 0, stream>>>(pA, pB, pD, -1.f, 15.f);
    bmm256_kernel<<<dim3(16, 32), 256, 0, stream>>>(pA, pD, pB, -1.f, 13.f);
    bmm256_kernel<<<dim3(16, 32), 256, 0, stream>>>(pz, pB, pD, 0.25f, 0.f);
    std::swap(pz, pD);
  }

  // T = softmax(q_land @ k^T) @ v        [bh,256,64]
  flash_kernel<<<dim3(8, 32), 256, 0, stream>>>(qlh, k, v, T, 256, 8192);
  // U = z @ T                            [bh,256,64]
  zu_kernel<<<dim3(256, 32), 64, 0, stream>>>(pz, T, U);
  // outh = softmax(q @ k_land^T) @ U     [bh,8192,64]
  flash_kernel<<<dim3(256, 32), 256, 0, stream>>>(q, klh, U, outh, 8192, 256);
  // outh += depthwise conv residual of v
  conv_kernel<<<dim3(2048, 32), 256, 0, stream>>>(v, convw, outh);
  // d_out = x + concat_heads(outh) @ w_out + b_out
  out_gemm<<<dim3(8, 512), 256, 0, stream>>>(outh, wout, x, bout, out);
}

// Round 3
// 2370.840 us; speedup vs baseline: 1.7071x; 1.7071x over previous
//
#include <hip/hip_runtime.h>
#include <hip/hip_bf16.h>
#include <utility>

// Shapes: b=4, n=8192, d=512, h=8, dh=64, m=256 landmarks, l=32, conv k=33. bh=32.
// Round 3: qkv/out GEMMs -> bf16 MFMA (16x16x32, 128x128 tile, BK=32,
// global_load_lds staging). pinv path stays fp32. flash stays fp32 VALU.

typedef unsigned short ushort_t;
typedef __attribute__((ext_vector_type(8))) short short8;
typedef __attribute__((ext_vector_type(4))) float f32x4;

#define GPTR(p) ((const __attribute__((address_space(1))) void*)(p))
#define LPTR(p) ((__attribute__((address_space(3))) void*)(p))

__device__ inline float bf2f(ushort_t u) {
  union { unsigned int i; float f; } x; x.i = ((unsigned int)u) << 16; return x.f;
}
__device__ inline ushort_t f2bf(float f) {
  union { float f; unsigned int i; } x; x.f = f;
  unsigned int r = x.i + 0x7FFF + ((x.i >> 16) & 1);   // round-nearest-even
  return (ushort_t)(r >> 16);
}

// ---------------- LayerNorm -> bf16 [32768][512] ----------------
__global__ __launch_bounds__(256) void ln_bf16(const float* __restrict__ x,
                                               const float* __restrict__ g,
                                               const float* __restrict__ be,
                                               ushort_t* __restrict__ out) {
  int row = blockIdx.x; int t = threadIdx.x;
  const float* xr = x + (size_t)row * 512;
  float v0 = xr[t], v1 = xr[t + 256];
  __shared__ float rs[256], rq[256];
  rs[t] = v0 + v1; rq[t] = v0 * v0 + v1 * v1;
  __syncthreads();
  for (int off = 128; off > 0; off >>= 1) {
    if (t < off) { rs[t] += rs[t + off]; rq[t] += rq[t + off]; }
    __syncthreads();
  }
  float mu = rs[0] * (1.f / 512.f);
  float var = rq[0] * (1.f / 512.f) - mu * mu;
  float rstd = rsqrtf(var + 1e-5f);
  ushort_t* orow = out + (size_t)row * 512;
  orow[t]       = f2bf((v0 - mu) * rstd * g[t]       + be[t]);
  orow[t + 256] = f2bf((v1 - mu) * rstd * g[t + 256] + be[t + 256]);
}

// ------------- weight transpose+convert: in [K][N] f32 -> out [N][K] bf16 ---
__global__ __launch_bounds__(256) void wtrans(const float* __restrict__ in,
                                              ushort_t* __restrict__ outw,
                                              int K, int N) {
  __shared__ float tile[64][65];
  int kb = blockIdx.x * 64, nb = blockIdx.y * 64, t = threadIdx.x;
  for (int i = t; i < 4096; i += 256) {
    int r = i >> 6, c = i & 63;
    tile[r][c] = in[(size_t)(kb + r) * N + nb + c];
  }
  __syncthreads();
  for (int i = t; i < 4096; i += 256) {
    int r = i >> 6, c = i & 63;
    outw[(size_t)(nb + r) * K + kb + c] = f2bf(tile[c][r]);
  }
}

// ------------- MFMA GEMM: [32768,512](bf16) @ Wt[1536,512]^T -> q/k/v -------
// 128x128 tile, BK=32, 4 waves (2x2), 16 MFMAs/wave/K-step.
__global__ __launch_bounds__(256) void gemm_qkv_mfma(const short* __restrict__ Abf,
                                                     const short* __restrict__ Wt,
                                                     ushort_t* __restrict__ q,
                                                     ushort_t* __restrict__ k,
                                                     ushort_t* __restrict__ v) {
  int bm0 = blockIdx.x * 128, bn0 = blockIdx.y * 128;
  __shared__ __align__(16) short As[128 * 32];
  __shared__ __align__(16) short Bs[128 * 32];
  int t = threadIdx.x, l = t & 63, w = t >> 6;
  int wr = w >> 1, wc = w & 1;
  int arow = w * 32 + (l >> 2);        // staging row (per lane)
  int akoff = (l & 3) * 8;             // staging k-offset (elements)
  const short* ag = Abf + (size_t)(bm0 + arow) * 512 + akoff;
  const short* bg = Wt + (size_t)(bn0 + arow) * 512 + akoff;
  short* Adst = As + w * 1024;         // wave-uniform LDS dst
  short* Bdst = Bs + w * 1024;
  int lr = l & 15, lk = (l >> 4) * 8;
  const short* Ard = As + (wr * 64 + lr) * 32 + lk;
  const short* Brd = Bs + (wc * 64 + lr) * 32 + lk;
  f32x4 acc[16];
#pragma unroll
  for (int i = 0; i < 16; i++) acc[i] = (f32x4){0.f, 0.f, 0.f, 0.f};
  for (int k0 = 0; k0 < 512; k0 += 32) {
    __builtin_amdgcn_global_load_lds(GPTR(ag + k0), LPTR(Adst), 16, 0, 0);
    __builtin_amdgcn_global_load_lds(GPTR(ag + k0 + 16 * 512), LPTR(Adst + 512), 16, 0, 0);
    __builtin_amdgcn_global_load_lds(GPTR(bg + k0), LPTR(Bdst), 16, 0, 0);
    __builtin_amdgcn_global_load_lds(GPTR(bg + k0 + 16 * 512), LPTR(Bdst + 512), 16, 0, 0);
    __syncthreads();
    short8 af[4], bf[4];
#pragma unroll
    for (int mf = 0; mf < 4; mf++) af[mf] = *(const short8*)(Ard + mf * 512);
#pragma unroll
    for (int nf = 0; nf < 4; nf++) bf[nf] = *(const short8*)(Brd + nf * 512);
#pragma unroll
    for (int mf = 0; mf < 4; mf++)
#pragma unroll
      for (int nf = 0; nf < 4; nf++)
        acc[mf * 4 + nf] = __builtin_amdgcn_mfma_f32_16x16x32_bf16(af[mf], bf[nf], acc[mf * 4 + nf], 0, 0, 0);
    __syncthreads();
  }
#pragma unroll
  for (int mf = 0; mf < 4; mf++)
#pragma unroll
    for (int nf = 0; nf < 4; nf++) {
      int gn = bn0 + wc * 64 + nf * 16 + (l & 15);
      int part = gn >> 9, head = (gn >> 6) & 7, d = gn & 63;
      int rbase = bm0 + wr * 64 + mf * 16 + ((l >> 4) << 2);
#pragma unroll
      for (int i = 0; i < 4; i++) {
        int gm = rbase + i;
        size_t dst = ((size_t)((gm >> 13) * 8 + head) * 8192 + (gm & 8191)) * 64 + d;
        float val = acc[mf * 4 + nf][i];
        if (part == 0) q[dst] = f2bf(val * 0.125f);
        else if (part == 1) k[dst] = f2bf(val);
        else v[dst] = f2bf(val);
      }
    }
}

// ------------- MFMA GEMM: gather(outh)[32768,512] @ Woutt^T + x + b -> out --
__global__ __launch_bounds__(256) void gemm_out_mfma(const ushort_t* __restrict__ outh,
                                                     const short* __restrict__ Wt,
                                                     const float* __restrict__ x,
                                                     const float* __restrict__ bo,
                                                     float* __restrict__ out) {
  int bm0 = blockIdx.x * 128, bn0 = blockIdx.y * 128;
  __shared__ __align__(16) short As[128 * 32];
  __shared__ __align__(16) short Bs[128 * 32];
  int t = threadIdx.x, l = t & 63, w = t >> 6;
  int wr = w >> 1, wc = w & 1;
  int arow = w * 32 + (l >> 2);
  int akoff = (l & 3) * 8;
  int gm0 = bm0 + arow, gm1 = gm0 + 16;
  const short* bg = Wt + (size_t)(bn0 + arow) * 512 + akoff;
  short* Adst = As + w * 1024;
  short* Bdst = Bs + w * 1024;
  int lr = l & 15, lk = (l >> 4) * 8;
  const short* Ard = As + (wr * 64 + lr) * 32 + lk;
  const short* Brd = Bs + (wc * 64 + lr) * 32 + lk;
  f32x4 acc[16];
#pragma unroll
  for (int i = 0; i < 16; i++) acc[i] = (f32x4){0.f, 0.f, 0.f, 0.f};
  for (int k0 = 0; k0 < 512; k0 += 32) {
    int kk = k0 + akoff;
    const ushort_t* a0 = outh + ((size_t)((gm0 >> 13) * 8 + (kk >> 6)) * 8192 + (gm0 & 8191)) * 64 + (kk & 63);
    const ushort_t* a1 = outh + ((size_t)((gm1 >> 13) * 8 + (kk >> 6)) * 8192 + (gm1 & 8191)) * 64 + (kk & 63);
    __builtin_amdgcn_global_load_lds(GPTR(a0), LPTR(Adst), 16, 0, 0);
    __builtin_amdgcn_global_load_lds(GPTR(a1), LPTR(Adst + 512), 16, 0, 0);
    __builtin_amdgcn_global_load_lds(GPTR(bg + k0), LPTR(Bdst), 16, 0, 0);
    __builtin_amdgcn_global_load_lds(GPTR(bg + k0 + 16 * 512), LPTR(Bdst + 512), 16, 0, 0);
    __syncthreads();
    short8 af[4], bf[4];
#pragma unroll
    for (int mf = 0; mf < 4; mf++) af[mf] = *(const short8*)(Ard + mf * 512);
#pragma unroll
    for (int nf = 0; nf < 4; nf++) bf[nf] = *(const short8*)(Brd + nf * 512);
#pragma unroll
    for (int mf = 0; mf < 4; mf++)
#pragma unroll
      for (int nf = 0; nf < 4; nf++)
        acc[mf * 4 + nf] = __builtin_amdgcn_mfma_f32_16x16x32_bf16(af[mf], bf[nf], acc[mf * 4 + nf], 0, 0, 0);
    __syncthreads();
  }
#pragma unroll
  for (int mf = 0; mf < 4; mf++)
#pragma unroll
    for (int nf = 0; nf < 4; nf++) {
      int gn = bn0 + wc * 64 + nf * 16 + (l & 15);
      int rbase = bm0 + wr * 64 + mf * 16 + ((l >> 4) << 2);
#pragma unroll
      for (int i = 0; i < 4; i++) {
        int gm = rbase + i;
        size_t o = (size_t)gm * 512 + gn;
        out[o] = x[o] + bo[gn] + acc[mf * 4 + nf][i];
      }
    }
}

// --------- landmarks: mean over 32 rows; fp32 (for sim2) + bf16 copies ------
__global__ void land_kernel(const ushort_t* __restrict__ q, const ushort_t* __restrict__ k,
                            float* __restrict__ qlf, float* __restrict__ klf,
                            ushort_t* __restrict__ qlh, ushort_t* __restrict__ klh) {
  int bh = blockIdx.y, mi = blockIdx.x, d = threadIdx.x;  // 64 threads
  size_t base = ((size_t)bh * 8192 + (size_t)mi * 32) * 64 + d;
  float sq = 0.f, sk = 0.f;
  for (int j = 0; j < 32; j++) {
    sq += bf2f(q[base + (size_t)j * 64]);
    sk += bf2f(k[base + (size_t)j * 64]);
  }
  size_t o = ((size_t)bh * 256 + mi) * 64 + d;
  float aq = sq * (1.f / 32.f), ak = sk * (1.f / 32.f);
  qlf[o] = aq; klf[o] = ak;
  qlh[o] = f2bf(aq); klh[o] = f2bf(ak);
}

// ------------- sim2 + softmax -> attn2 [32][256][256] fp32 -----------------
__global__ __launch_bounds__(256) void sim2_kernel(const float* __restrict__ ql,
                                                   const float* __restrict__ kl,
                                                   float* __restrict__ attn2) {
  int bh = blockIdx.y, row = blockIdx.x, t = threadIdx.x;
  __shared__ float qrow[64];
  __shared__ float red[256];
  if (t < 64) qrow[t] = ql[((size_t)bh * 256 + row) * 64 + t];
  __syncthreads();
  const float* kr = kl + ((size_t)bh * 256 + t) * 64;
  float s = 0.f;
#pragma unroll
  for (int kd = 0; kd < 64; kd++) s = fmaf(qrow[kd], kr[kd], s);
  red[t] = s; __syncthreads();
  for (int off = 128; off > 0; off >>= 1) { if (t < off) red[t] = fmaxf(red[t], red[t + off]); __syncthreads(); }
  float mx = red[0]; __syncthreads();
  float pv = __expf(s - mx);
  red[t] = pv; __syncthreads();
  for (int off = 128; off > 0; off >>= 1) { if (t < off) red[t] += red[t + off]; __syncthreads(); }
  float inv = 1.f / red[0];
  attn2[((size_t)bh * 256 + row) * 256 + t] = pv * inv;
}

// ------------- pinv init helpers (fp32) ------------------------------------
__global__ __launch_bounds__(256) void abssum_kernel(const float* __restrict__ x,
                                                     float* __restrict__ rowsum,
                                                     float* __restrict__ colsum) {
  int bh = blockIdx.x, t = threadIdx.x;
  const float* xb = x + ((size_t)bh << 16);
  float s = 0.f;
  for (int c = 0; c < 256; c++) s += fabsf(xb[(size_t)t * 256 + c]);
  rowsum[bh * 256 + t] = s;
  float s2 = 0.f;
  for (int r = 0; r < 256; r++) s2 += fabsf(xb[(size_t)r * 256 + t]);
  colsum[bh * 256 + t] = s2;
}

__global__ __launch_bounds__(256) void pinv_scale_kernel(const float* __restrict__ rowsum,
                                                         const float* __restrict__ colsum,
                                                         float* __restrict__ scl) {
  int t = threadIdx.x;
  float m1 = 0.f, m2 = 0.f;
  for (int i = t; i < 8192; i += 256) { m1 = fmaxf(m1, rowsum[i]); m2 = fmaxf(m2, colsum[i]); }
  __shared__ float r1[256], r2[256];
  r1[t] = m1; r2[t] = m2; __syncthreads();
  for (int off = 128; off > 0; off >>= 1) {
    if (t < off) { r1[t] = fmaxf(r1[t], r1[t + off]); r2[t] = fmaxf(r2[t], r2[t + off]); }
    __syncthreads();
  }
  if (t == 0) scl[0] = 1.f / (r1[0] * r2[0]);
}

__global__ __launch_bounds__(256) void zinit_kernel(const float* __restrict__ x,
                                                    const float* __restrict__ scl,
                                                    float* __restrict__ z) {
  int bh = blockIdx.y, i = blockIdx.x, j = threadIdx.x;
  float s = scl[0];
  z[((size_t)bh << 16) + (size_t)i * 256 + j] = x[((size_t)bh << 16) + (size_t)j * 256 + i] * s;
}

// ------------- batched 256x256 GEMM: C = diagc*I + alpha*(A@B), fp32 --------
__global__ __launch_bounds__(256) void bmm256_kernel(const float* __restrict__ A,
                                                     const float* __restrict__ B,
                                                     float* __restrict__ C,
                                                     float alpha, float diagc) {
  int bh = blockIdx.y, tile = blockIdx.x;
  int bm0 = (tile >> 2) << 6, bn0 = (tile & 3) << 6;
  const float* Ab = A + ((size_t)bh << 16);
  const float* Bb = B + ((size_t)bh << 16);
  float* Cb = C + ((size_t)bh << 16);
  __shared__ float As[32][65];
  __shared__ float Bs[32][65];
  int t = threadIdx.x, tm = t >> 4, tn = t & 15;
  float acc[16];
#pragma unroll
  for (int i = 0; i < 16; i++) acc[i] = 0.f;
  for (int k0 = 0; k0 < 256; k0 += 32) {
#pragma unroll
    for (int i = 0; i < 8; i++) {
      int idx = t + (i << 8); int r = idx >> 5, c = idx & 31;
      As[c][r] = Ab[(size_t)(bm0 + r) * 256 + k0 + c];
    }
#pragma unroll
    for (int i = 0; i < 8; i++) {
      int idx = t + (i << 8); int r = idx >> 6, c = idx & 63;
      Bs[r][c] = Bb[(size_t)(k0 + r) * 256 + bn0 + c];
    }
    __syncthreads();
#pragma unroll
    for (int kk = 0; kk < 32; kk++) {
      float a[4], b[4];
#pragma unroll
      for (int i = 0; i < 4; i++) { a[i] = As[kk][tm * 4 + i]; b[i] = Bs[kk][tn * 4 + i]; }
#pragma unroll
      for (int i = 0; i < 4; i++)
#pragma unroll
        for (int j = 0; j < 4; j++) acc[i * 4 + j] = fmaf(a[i], b[j], acc[i * 4 + j]);
    }
    __syncthreads();
  }
#pragma unroll
  for (int i = 0; i < 4; i++)
#pragma unroll
    for (int j = 0; j < 4; j++) {
      int gm = bm0 + tm * 4 + i, gn = bn0 + tn * 4 + j;
      Cb[(size_t)gm * 256 + gn] = alpha * acc[i * 4 + j] + (gm == gn ? diagc : 0.f);
    }
}

__global__ __launch_bounds__(256) void iminus_kernel(const float* __restrict__ A,
                                                     float* __restrict__ G, float c0) {
  size_t idx = (size_t)blockIdx.x * 256 + threadIdx.x;
  int r = (int)((idx >> 8) & 255), c = (int)(idx & 255);
  G[idx] = (r == c ? c0 : 0.f) - A[idx];
}

// ------------- fused flash (all bf16 in, bf16 out, fp32 math) ---------------
__global__ __launch_bounds__(256) void flash_kernel(const ushort_t* __restrict__ qsrc,
                                                    const ushort_t* __restrict__ ksrc,
                                                    const ushort_t* __restrict__ vsrc,
                                                    ushort_t* __restrict__ out,
                                                    int nq, int nkv) {
  int bh = blockIdx.y;
  int q0 = blockIdx.x * 32;
  int t = threadIdx.x, rg = t >> 3, sl = t & 7;
  __shared__ float qs[32 * 68];
  __shared__ float ks[64 * 68];
  __shared__ float vs[64 * 64];
  __shared__ float ps[32 * 65];
  {
    int r = t >> 3, c8 = (t & 7) << 3;
    uint4 u = *(const uint4*)(qsrc + ((size_t)bh * nq + q0 + r) * 64 + c8);
    const ushort_t* s = (const ushort_t*)&u;
#pragma unroll
    for (int j = 0; j < 8; j++) qs[r * 68 + c8 + j] = bf2f(s[j]);
  }
  __syncthreads();
  float4 qreg[16];
#pragma unroll
  for (int i = 0; i < 16; i++) qreg[i] = *(const float4*)&qs[rg * 68 + i * 4];
  float acc[8];
#pragma unroll
  for (int i = 0; i < 8; i++) acc[i] = 0.f;
  float mrun = -1e30f, lrun = 0.f;
  for (int n0 = 0; n0 < nkv; n0 += 64) {
    __syncthreads();
    for (int i = t; i < 512; i += 256) {
      int r = i >> 3, c8 = (i & 7) << 3;
      uint4 uk = *(const uint4*)(ksrc + ((size_t)bh * nkv + n0 + r) * 64 + c8);
      uint4 uv = *(const uint4*)(vsrc + ((size_t)bh * nkv + n0 + r) * 64 + c8);
      const ushort_t* sk = (const ushort_t*)&uk;
      const ushort_t* sv = (const ushort_t*)&uv;
#pragma unroll
      for (int j = 0; j < 8; j++) {
        ks[r * 68 + c8 + j] = bf2f(sk[j]);
        vs[r * 64 + c8 + j] = bf2f(sv[j]);
      }
    }
    __syncthreads();
    float sc[8]; float tmax = -1e30f;
#pragma unroll
    for (int jj = 0; jj < 8; jj++) {
      int c = sl + (jj << 3);
      const float4* krow = (const float4*)&ks[c * 68];
      float s = 0.f;
#pragma unroll
      for (int i = 0; i < 16; i++) {
        float4 kv = krow[i], qv = qreg[i];
        s += qv.x * kv.x + qv.y * kv.y + qv.z * kv.z + qv.w * kv.w;
      }
      sc[jj] = s; tmax = fmaxf(tmax, s);
    }
#pragma unroll
    for (int off = 1; off < 8; off <<= 1) tmax = fmaxf(tmax, __shfl_xor(tmax, off));
    float mnew = fmaxf(mrun, tmax);
    float scalef = __expf(mrun - mnew);
    float tsum = 0.f;
#pragma unroll
    for (int jj = 0; jj < 8; jj++) {
      float pp = __expf(sc[jj] - mnew);
      ps[rg * 65 + sl + (jj << 3)] = pp;
      tsum += pp;
    }
#pragma unroll
    for (int off = 1; off < 8; off <<= 1) tsum += __shfl_xor(tsum, off);
    lrun = lrun * scalef + tsum;
    mrun = mnew;
    __syncthreads();
#pragma unroll
    for (int dd = 0; dd < 8; dd++) acc[dd] *= scalef;
    const int dbase = sl << 3;
    for (int c = 0; c < 64; c++) {
      float pp = ps[rg * 65 + c];
      const float4* vr = (const float4*)&vs[c * 64 + dbase];
      float4 v0 = vr[0], v1 = vr[1];
      acc[0] = fmaf(pp, v0.x, acc[0]); acc[1] = fmaf(pp, v0.y, acc[1]);
      acc[2] = fmaf(pp, v0.z, acc[2]); acc[3] = fmaf(pp, v0.w, acc[3]);
      acc[4] = fmaf(pp, v1.x, acc[4]); acc[5] = fmaf(pp, v1.y, acc[5]);
      acc[6] = fmaf(pp, v1.z, acc[6]); acc[7] = fmaf(pp, v1.w, acc[7]);
    }
  }
  float invl = 1.f / lrun;
  union { ushort_t s[8]; uint4 u; } ob;
#pragma unroll
  for (int j = 0; j < 8; j++) ob.s[j] = f2bf(acc[j] * invl);
  *(uint4*)(out + ((size_t)bh * nq + q0 + rg) * 64 + (sl << 3)) = ob.u;
}

// ------------- U = z @ T  (z fp32 [256,256], T bf16 [256,64]) ---------------
__global__ void zu_kernel(const float* __restrict__ z, const ushort_t* __restrict__ T,
                          ushort_t* __restrict__ U) {
  int bh = blockIdx.y, r = blockIdx.x, d = threadIdx.x;  // 64 threads
  const float* zr = z + ((size_t)bh << 16) + ((size_t)r << 8);
  float s = 0.f;
  for (int c = 0; c < 256; c++) s = fmaf(zr[c], bf2f(T[((size_t)bh * 256 + c) * 64 + d]), s);
  U[((size_t)bh * 256 + r) * 64 + d] = f2bf(s);
}

// ------------- depthwise residual conv over n (k=33), adds into outh -------
__global__ __launch_bounds__(256) void conv_kernel(const ushort_t* __restrict__ v,
                                                   const float* __restrict__ w,
                                                   ushort_t* __restrict__ outh) {
  int bh = blockIdx.y;
  int nr = blockIdx.x * 4 + (threadIdx.x >> 6);
  int d = threadIdx.x & 63, h = bh & 7;
  float s = 0.f;
#pragma unroll
  for (int kk = 0; kk < 33; kk++) {
    int nn = nr + kk - 16;
    if (nn >= 0 && nn < 8192)
      s = fmaf(w[h * 33 + kk], bf2f(v[((size_t)bh * 8192 + nn) * 64 + d]), s);
  }
  size_t o = ((size_t)bh * 8192 + nr) * 64 + d;
  outh[o] = f2bf(bf2f(outh[o]) + s);
}

extern "C" void kernel_launch(void* const* d_in, const int* in_sizes, int n_in,
                              void* d_out, int out_size, void* d_ws, size_t ws_size,
                              hipStream_t stream) {
  (void)in_sizes; (void)n_in; (void)out_size; (void)ws_size;
  const float* x     = (const float*)d_in[0];
  const float* g     = (const float*)d_in[1];
  const float* be    = (const float*)d_in[2];
  const float* wqkv  = (const float*)d_in[3];
  const float* wout  = (const float*)d_in[4];
  const float* bout  = (const float*)d_in[5];
  const float* convw = (const float*)d_in[6];
  float* out = (float*)d_out;

  char* base = (char*)d_ws;
  size_t off = 0;
  auto alloc = [&](size_t bytes) -> void* {
    void* r = base + off; off = (off + bytes + 255) & ~(size_t)255; return r;
  };
  const size_t NBH = (size_t)32 * 8192 * 64;
  ushort_t* q     = (ushort_t*)alloc(NBH * 2);
  ushort_t* k     = (ushort_t*)alloc(NBH * 2);
  ushort_t* v     = (ushort_t*)alloc(NBH * 2);
  ushort_t* outh  = (ushort_t*)alloc(NBH * 2);
  float*    qlf   = (float*)alloc((size_t)32 * 256 * 64 * 4);
  float*    klf   = (float*)alloc((size_t)32 * 256 * 64 * 4);
  ushort_t* qlh   = (ushort_t*)alloc((size_t)32 * 256 * 64 * 2);
  ushort_t* klh   = (ushort_t*)alloc((size_t)32 * 256 * 64 * 2);
  float*    attn2 = (float*)alloc((size_t)32 * 256 * 256 * 4);
  float*    z0    = (float*)alloc((size_t)32 * 256 * 256 * 4);
  float*    b1    = (float*)alloc((size_t)32 * 256 * 256 * 4);
  float*    b2    = (float*)alloc((size_t)32 * 256 * 256 * 4);
  float*    b3    = (float*)alloc((size_t)32 * 256 * 256 * 4);
  float*    rowsum = (float*)alloc(8192 * 4);
  float*    colsum = (float*)alloc(8192 * 4);
  float*    scl   = (float*)alloc(64);
  ushort_t* T     = (ushort_t*)alloc((size_t)32 * 256 * 64 * 2);
  ushort_t* U     = (ushort_t*)alloc((size_t)32 * 256 * 64 * 2);
  ushort_t* Wqkvt = (ushort_t*)alloc((size_t)1536 * 512 * 2);
  ushort_t* Woutt = (ushort_t*)alloc((size_t)512 * 512 * 2);
  // Abf (33.5 MB) aliases the attn2..b3 region (42 MB): Abf is dead before
  // sim2_kernel writes attn2.
  short* Abf = (short*)attn2;

  ln_bf16<<<32768, 256, 0, stream>>>(x, g, be, (ushort_t*)Abf);
  wtrans<<<dim3(8, 24), 256, 0, stream>>>(wqkv, Wqkvt, 512, 1536);
  wtrans<<<dim3(8, 8), 256, 0, stream>>>(wout, Woutt, 512, 512);
  gemm_qkv_mfma<<<dim3(256, 12), 256, 0, stream>>>(Abf, (const short*)Wqkvt, q, k, v);
  land_kernel<<<dim3(256, 32), 64, 0, stream>>>(q, k, qlf, klf, qlh, klh);
  sim2_kernel<<<dim3(256, 32), 256, 0, stream>>>(qlf, klf, attn2);
  abssum_kernel<<<32, 256, 0, stream>>>(attn2, rowsum, colsum);
  pinv_scale_kernel<<<1, 256, 0, stream>>>(rowsum, colsum, scl);
  zinit_kernel<<<dim3(256, 32), 256, 0, stream>>>(attn2, scl, z0);

  float* pz = z0; float* pA = b1; float* pB = b2; float* pD = b3;
  for (int it = 0; it < 6; it++) {
    bmm256_kernel<<<dim3(16, 32), 256, 0, stream>>>(attn2, pz, pA, 1.f, 0.f);
    iminus_kernel<<<8192, 256, 0, stream>>>(pA, pB, 7.f);
    bmm256_kernel<<<dim3(16, 32), 256, 0, stream>>>(pA, pB, pD, -1.f, 15.f);
    bmm256_kernel<<<dim3(16, 32), 256, 0, stream>>>(pA, pD, pB, -1.f, 13.f);
    bmm256_kernel<<<dim3(16, 32), 256, 0, stream>>>(pz, pB, pD, 0.25f, 0.f);
    std::swap(pz, pD);
  }

  // T = softmax(q_land @ k^T) @ v        [bh,256,64]
  flash_kernel<<<dim3(8, 32), 256, 0, stream>>>(qlh, k, v, T, 256, 8192);
  // U = z @ T                            [bh,256,64]
  zu_kernel<<<dim3(256, 32), 64, 0, stream>>>(pz, T, U);
  // outh = softmax(q @ k_land^T) @ U     [bh,8192,64]
  flash_kernel<<<dim3(256, 32), 256, 0, stream>>>(q, klh, U, outh, 8192, 256);
  // outh += depthwise conv residual of v
  conv_kernel<<<dim3(2048, 32), 256, 0, stream>>>(v, convw, outh);
  // d_out = x + concat_heads(outh) @ w_out + b_out
  gemm_out_mfma<<<dim3(256, 4), 256, 0, stream>>>(outh, (const short*)Woutt, x, bout, out);
}

// Round 4
// 1195.779 us; speedup vs baseline: 3.3846x; 1.9827x over previous
//
#include <hip/hip_runtime.h>
#include <hip/hip_bf16.h>
#include <utility>

// Shapes: b=4, n=8192, d=512, h=8, dh=64, m=256 landmarks, l=32, conv k=33. bh=32.
// Round 4: flash attention -> bf16 MFMA (32x32x16, swapped QK^T, register P via
// pack+shfl_xor(32), XOR-swizzled K/VT LDS staging). V stored transposed (vT).

typedef unsigned short ushort_t;
typedef __attribute__((ext_vector_type(8))) short short8;
typedef __attribute__((ext_vector_type(4))) float f32x4;
typedef __attribute__((ext_vector_type(16))) float f32x16;

#define GPTR(p) ((const __attribute__((address_space(1))) void*)(p))
#define LPTR(p) ((__attribute__((address_space(3))) void*)(p))

__device__ inline float bf2f(ushort_t u) {
  union { unsigned int i; float f; } x; x.i = ((unsigned int)u) << 16; return x.f;
}
__device__ inline ushort_t f2bf(float f) {
  union { float f; unsigned int i; } x; x.f = f;
  unsigned int r = x.i + 0x7FFF + ((x.i >> 16) & 1);   // round-nearest-even
  return (ushort_t)(r >> 16);
}

// ---------------- LayerNorm -> bf16 [32768][512] ----------------
__global__ __launch_bounds__(256) void ln_bf16(const float* __restrict__ x,
                                               const float* __restrict__ g,
                                               const float* __restrict__ be,
                                               ushort_t* __restrict__ out) {
  int row = blockIdx.x; int t = threadIdx.x;
  const float* xr = x + (size_t)row * 512;
  float v0 = xr[t], v1 = xr[t + 256];
  __shared__ float rs[256], rq[256];
  rs[t] = v0 + v1; rq[t] = v0 * v0 + v1 * v1;
  __syncthreads();
  for (int off = 128; off > 0; off >>= 1) {
    if (t < off) { rs[t] += rs[t + off]; rq[t] += rq[t + off]; }
    __syncthreads();
  }
  float mu = rs[0] * (1.f / 512.f);
  float var = rq[0] * (1.f / 512.f) - mu * mu;
  float rstd = rsqrtf(var + 1e-5f);
  ushort_t* orow = out + (size_t)row * 512;
  orow[t]       = f2bf((v0 - mu) * rstd * g[t]       + be[t]);
  orow[t + 256] = f2bf((v1 - mu) * rstd * g[t + 256] + be[t + 256]);
}

// ------------- weight transpose+convert: in [K][N] f32 -> out [N][K] bf16 ---
__global__ __launch_bounds__(256) void wtrans(const float* __restrict__ in,
                                              ushort_t* __restrict__ outw,
                                              int K, int N) {
  __shared__ float tile[64][65];
  int kb = blockIdx.x * 64, nb = blockIdx.y * 64, t = threadIdx.x;
  for (int i = t; i < 4096; i += 256) {
    int r = i >> 6, c = i & 63;
    tile[r][c] = in[(size_t)(kb + r) * N + nb + c];
  }
  __syncthreads();
  for (int i = t; i < 4096; i += 256) {
    int r = i >> 6, c = i & 63;
    outw[(size_t)(nb + r) * K + kb + c] = f2bf(tile[c][r]);
  }
}

// ------------- MFMA GEMM: [32768,512](bf16) @ Wt[1536,512]^T -> q/k/vT ------
__global__ __launch_bounds__(256) void gemm_qkv_mfma(const short* __restrict__ Abf,
                                                     const short* __restrict__ Wt,
                                                     ushort_t* __restrict__ q,
                                                     ushort_t* __restrict__ k,
                                                     ushort_t* __restrict__ vT) {
  int bm0 = blockIdx.x * 128, bn0 = blockIdx.y * 128;
  __shared__ __align__(16) short As[128 * 32];
  __shared__ __align__(16) short Bs[128 * 32];
  int t = threadIdx.x, l = t & 63, w = t >> 6;
  int wr = w >> 1, wc = w & 1;
  int arow = w * 32 + (l >> 2);
  int akoff = (l & 3) * 8;
  const short* ag = Abf + (size_t)(bm0 + arow) * 512 + akoff;
  const short* bg = Wt + (size_t)(bn0 + arow) * 512 + akoff;
  short* Adst = As + w * 1024;
  short* Bdst = Bs + w * 1024;
  int lr = l & 15, lk = (l >> 4) * 8;
  const short* Ard = As + (wr * 64 + lr) * 32 + lk;
  const short* Brd = Bs + (wc * 64 + lr) * 32 + lk;
  f32x4 acc[16];
#pragma unroll
  for (int i = 0; i < 16; i++) acc[i] = (f32x4){0.f, 0.f, 0.f, 0.f};
  for (int k0 = 0; k0 < 512; k0 += 32) {
    __builtin_amdgcn_global_load_lds(GPTR(ag + k0), LPTR(Adst), 16, 0, 0);
    __builtin_amdgcn_global_load_lds(GPTR(ag + k0 + 16 * 512), LPTR(Adst + 512), 16, 0, 0);
    __builtin_amdgcn_global_load_lds(GPTR(bg + k0), LPTR(Bdst), 16, 0, 0);
    __builtin_amdgcn_global_load_lds(GPTR(bg + k0 + 16 * 512), LPTR(Bdst + 512), 16, 0, 0);
    __syncthreads();
    short8 af[4], bf[4];
#pragma unroll
    for (int mf = 0; mf < 4; mf++) af[mf] = *(const short8*)(Ard + mf * 512);
#pragma unroll
    for (int nf = 0; nf < 4; nf++) bf[nf] = *(const short8*)(Brd + nf * 512);
#pragma unroll
    for (int mf = 0; mf < 4; mf++)
#pragma unroll
      for (int nf = 0; nf < 4; nf++)
        acc[mf * 4 + nf] = __builtin_amdgcn_mfma_f32_16x16x32_bf16(af[mf], bf[nf], acc[mf * 4 + nf], 0, 0, 0);
    __syncthreads();
  }
#pragma unroll
  for (int mf = 0; mf < 4; mf++)
#pragma unroll
    for (int nf = 0; nf < 4; nf++) {
      int gn = bn0 + wc * 64 + nf * 16 + (l & 15);
      int part = gn >> 9, head = (gn >> 6) & 7, d = gn & 63;
      int rbase = bm0 + wr * 64 + mf * 16 + ((l >> 4) << 2);
      int bhead = (rbase >> 13) * 8 + head;
      if (part == 2) {
        union { ushort_t s[4]; unsigned long long u; } p4;
#pragma unroll
        for (int i = 0; i < 4; i++) p4.s[i] = f2bf(acc[mf * 4 + nf][i]);
        *(unsigned long long*)(vT + ((size_t)bhead * 64 + d) * 8192 + (rbase & 8191)) = p4.u;
      } else {
#pragma unroll
        for (int i = 0; i < 4; i++) {
          int gm = rbase + i;
          size_t dst = ((size_t)bhead * 8192 + (gm & 8191)) * 64 + d;
          float val = acc[mf * 4 + nf][i];
          if (part == 0) q[dst] = f2bf(val * 0.125f);
          else k[dst] = f2bf(val);
        }
      }
    }
}

// ------------- MFMA GEMM: gather(outh)[32768,512] @ Woutt^T + x + b -> out --
__global__ __launch_bounds__(256) void gemm_out_mfma(const ushort_t* __restrict__ outh,
                                                     const short* __restrict__ Wt,
                                                     const float* __restrict__ x,
                                                     const float* __restrict__ bo,
                                                     float* __restrict__ out) {
  int bm0 = blockIdx.x * 128, bn0 = blockIdx.y * 128;
  __shared__ __align__(16) short As[128 * 32];
  __shared__ __align__(16) short Bs[128 * 32];
  int t = threadIdx.x, l = t & 63, w = t >> 6;
  int wr = w >> 1, wc = w & 1;
  int arow = w * 32 + (l >> 2);
  int akoff = (l & 3) * 8;
  int gm0 = bm0 + arow, gm1 = gm0 + 16;
  const short* bg = Wt + (size_t)(bn0 + arow) * 512 + akoff;
  short* Adst = As + w * 1024;
  short* Bdst = Bs + w * 1024;
  int lr = l & 15, lk = (l >> 4) * 8;
  const short* Ard = As + (wr * 64 + lr) * 32 + lk;
  const short* Brd = Bs + (wc * 64 + lr) * 32 + lk;
  f32x4 acc[16];
#pragma unroll
  for (int i = 0; i < 16; i++) acc[i] = (f32x4){0.f, 0.f, 0.f, 0.f};
  for (int k0 = 0; k0 < 512; k0 += 32) {
    int kk = k0 + akoff;
    const ushort_t* a0 = outh + ((size_t)((gm0 >> 13) * 8 + (kk >> 6)) * 8192 + (gm0 & 8191)) * 64 + (kk & 63);
    const ushort_t* a1 = outh + ((size_t)((gm1 >> 13) * 8 + (kk >> 6)) * 8192 + (gm1 & 8191)) * 64 + (kk & 63);
    __builtin_amdgcn_global_load_lds(GPTR(a0), LPTR(Adst), 16, 0, 0);
    __builtin_amdgcn_global_load_lds(GPTR(a1), LPTR(Adst + 512), 16, 0, 0);
    __builtin_amdgcn_global_load_lds(GPTR(bg + k0), LPTR(Bdst), 16, 0, 0);
    __builtin_amdgcn_global_load_lds(GPTR(bg + k0 + 16 * 512), LPTR(Bdst + 512), 16, 0, 0);
    __syncthreads();
    short8 af[4], bf[4];
#pragma unroll
    for (int mf = 0; mf < 4; mf++) af[mf] = *(const short8*)(Ard + mf * 512);
#pragma unroll
    for (int nf = 0; nf < 4; nf++) bf[nf] = *(const short8*)(Brd + nf * 512);
#pragma unroll
    for (int mf = 0; mf < 4; mf++)
#pragma unroll
      for (int nf = 0; nf < 4; nf++)
        acc[mf * 4 + nf] = __builtin_amdgcn_mfma_f32_16x16x32_bf16(af[mf], bf[nf], acc[mf * 4 + nf], 0, 0, 0);
    __syncthreads();
  }
#pragma unroll
  for (int mf = 0; mf < 4; mf++)
#pragma unroll
    for (int nf = 0; nf < 4; nf++) {
      int gn = bn0 + wc * 64 + nf * 16 + (l & 15);
      int rbase = bm0 + wr * 64 + mf * 16 + ((l >> 4) << 2);
#pragma unroll
      for (int i = 0; i < 4; i++) {
        int gm = rbase + i;
        size_t o = (size_t)gm * 512 + gn;
        out[o] = x[o] + bo[gn] + acc[mf * 4 + nf][i];
      }
    }
}

// --------- landmarks: mean over 32 rows; fp32 (for sim2) + bf16 copies ------
__global__ void land_kernel(const ushort_t* __restrict__ q, const ushort_t* __restrict__ k,
                            float* __restrict__ qlf, float* __restrict__ klf,
                            ushort_t* __restrict__ qlh, ushort_t* __restrict__ klh) {
  int bh = blockIdx.y, mi = blockIdx.x, d = threadIdx.x;  // 64 threads
  size_t base = ((size_t)bh * 8192 + (size_t)mi * 32) * 64 + d;
  float sq = 0.f, sk = 0.f;
  for (int j = 0; j < 32; j++) {
    sq += bf2f(q[base + (size_t)j * 64]);
    sk += bf2f(k[base + (size_t)j * 64]);
  }
  size_t o = ((size_t)bh * 256 + mi) * 64 + d;
  float aq = sq * (1.f / 32.f), ak = sk * (1.f / 32.f);
  qlf[o] = aq; klf[o] = ak;
  qlh[o] = f2bf(aq); klh[o] = f2bf(ak);
}

// ------------- sim2 + softmax -> attn2 [32][256][256] fp32 -----------------
__global__ __launch_bounds__(256) void sim2_kernel(const float* __restrict__ ql,
                                                   const float* __restrict__ kl,
                                                   float* __restrict__ attn2) {
  int bh = blockIdx.y, row = blockIdx.x, t = threadIdx.x;
  __shared__ float qrow[64];
  __shared__ float red[256];
  if (t < 64) qrow[t] = ql[((size_t)bh * 256 + row) * 64 + t];
  __syncthreads();
  const float* kr = kl + ((size_t)bh * 256 + t) * 64;
  float s = 0.f;
#pragma unroll
  for (int kd = 0; kd < 64; kd++) s = fmaf(qrow[kd], kr[kd], s);
  red[t] = s; __syncthreads();
  for (int off = 128; off > 0; off >>= 1) { if (t < off) red[t] = fmaxf(red[t], red[t + off]); __syncthreads(); }
  float mx = red[0]; __syncthreads();
  float pv = __expf(s - mx);
  red[t] = pv; __syncthreads();
  for (int off = 128; off > 0; off >>= 1) { if (t < off) red[t] += red[t + off]; __syncthreads(); }
  float inv = 1.f / red[0];
  attn2[((size_t)bh * 256 + row) * 256 + t] = pv * inv;
}

// ------------- pinv init helpers (fp32) ------------------------------------
__global__ __launch_bounds__(256) void abssum_kernel(const float* __restrict__ x,
                                                     float* __restrict__ rowsum,
                                                     float* __restrict__ colsum) {
  int bh = blockIdx.x, t = threadIdx.x;
  const float* xb = x + ((size_t)bh << 16);
  float s = 0.f;
  for (int c = 0; c < 256; c++) s += fabsf(xb[(size_t)t * 256 + c]);
  rowsum[bh * 256 + t] = s;
  float s2 = 0.f;
  for (int r = 0; r < 256; r++) s2 += fabsf(xb[(size_t)r * 256 + t]);
  colsum[bh * 256 + t] = s2;
}

__global__ __launch_bounds__(256) void pinv_scale_kernel(const float* __restrict__ rowsum,
                                                         const float* __restrict__ colsum,
                                                         float* __restrict__ scl) {
  int t = threadIdx.x;
  float m1 = 0.f, m2 = 0.f;
  for (int i = t; i < 8192; i += 256) { m1 = fmaxf(m1, rowsum[i]); m2 = fmaxf(m2, colsum[i]); }
  __shared__ float r1[256], r2[256];
  r1[t] = m1; r2[t] = m2; __syncthreads();
  for (int off = 128; off > 0; off >>= 1) {
    if (t < off) { r1[t] = fmaxf(r1[t], r1[t + off]); r2[t] = fmaxf(r2[t], r2[t + off]); }
    __syncthreads();
  }
  if (t == 0) scl[0] = 1.f / (r1[0] * r2[0]);
}

__global__ __launch_bounds__(256) void zinit_kernel(const float* __restrict__ x,
                                                    const float* __restrict__ scl,
                                                    float* __restrict__ z) {
  int bh = blockIdx.y, i = blockIdx.x, j = threadIdx.x;
  float s = scl[0];
  z[((size_t)bh << 16) + (size_t)i * 256 + j] = x[((size_t)bh << 16) + (size_t)j * 256 + i] * s;
}

// ------------- batched 256x256 GEMM: C = diagc*I + alpha*(A@B), fp32 --------
__global__ __launch_bounds__(256) void bmm256_kernel(const float* __restrict__ A,
                                                     const float* __restrict__ B,
                                                     float* __restrict__ C,
                                                     float alpha, float diagc) {
  int bh = blockIdx.y, tile = blockIdx.x;
  int bm0 = (tile >> 2) << 6, bn0 = (tile & 3) << 6;
  const float* Ab = A + ((size_t)bh << 16);
  const float* Bb = B + ((size_t)bh << 16);
  float* Cb = C + ((size_t)bh << 16);
  __shared__ float As[32][65];
  __shared__ float Bs[32][65];
  int t = threadIdx.x, tm = t >> 4, tn = t & 15;
  float acc[16];
#pragma unroll
  for (int i = 0; i < 16; i++) acc[i] = 0.f;
  for (int k0 = 0; k0 < 256; k0 += 32) {
#pragma unroll
    for (int i = 0; i < 8; i++) {
      int idx = t + (i << 8); int r = idx >> 5, c = idx & 31;
      As[c][r] = Ab[(size_t)(bm0 + r) * 256 + k0 + c];
    }
#pragma unroll
    for (int i = 0; i < 8; i++) {
      int idx = t + (i << 8); int r = idx >> 6, c = idx & 63;
      Bs[r][c] = Bb[(size_t)(k0 + r) * 256 + bn0 + c];
    }
    __syncthreads();
#pragma unroll
    for (int kk = 0; kk < 32; kk++) {
      float a[4], b[4];
#pragma unroll
      for (int i = 0; i < 4; i++) { a[i] = As[kk][tm * 4 + i]; b[i] = Bs[kk][tn * 4 + i]; }
#pragma unroll
      for (int i = 0; i < 4; i++)
#pragma unroll
        for (int j = 0; j < 4; j++) acc[i * 4 + j] = fmaf(a[i], b[j], acc[i * 4 + j]);
    }
    __syncthreads();
  }
#pragma unroll
  for (int i = 0; i < 4; i++)
#pragma unroll
    for (int j = 0; j < 4; j++) {
      int gm = bm0 + tm * 4 + i, gn = bn0 + tn * 4 + j;
      Cb[(size_t)gm * 256 + gn] = alpha * acc[i * 4 + j] + (gm == gn ? diagc : 0.f);
    }
}

__global__ __launch_bounds__(256) void iminus_kernel(const float* __restrict__ A,
                                                     float* __restrict__ G, float c0) {
  size_t idx = (size_t)blockIdx.x * 256 + threadIdx.x;
  int r = (int)((idx >> 8) & 255), c = (int)(idx & 255);
  G[idx] = (r == c ? c0 : 0.f) - A[idx];
}

// ------------- MFMA flash: out = softmax(qsrc @ ksrc^T) @ V ----------------
// qsrc [bh][nq][64], ksrc [bh][nkv][64], vts = V^T [bh][64][vt_stride].
// Swapped QK^T (S^T = mfma(K,Q)): lane owns one q-column; P stays in regs.
// write_partial=1: emit unnormalized O^T f32 + (m,l) per split chunk.
__global__ __launch_bounds__(256) void flash_mfma(
    const ushort_t* __restrict__ qsrc, const ushort_t* __restrict__ ksrc,
    const ushort_t* __restrict__ vts, ushort_t* __restrict__ outb,
    float* __restrict__ pOT, float* __restrict__ pM, float* __restrict__ pL,
    int nq, int nkv, int vt_stride, int nsplit, int write_partial) {
  __shared__ __align__(16) char smem[64 * 132 * 4];
  ushort_t* Ks = (ushort_t*)smem;            // 8 KB, XOR-swizzled chunks
  ushort_t* Vs = (ushort_t*)(smem + 8192);   // 8 KB (V^T tile)
  float* Ot = (float*)smem;                  // reused after main loop

  int t = threadIdx.x, l = t & 63, w = t >> 6, h = l >> 5, ql = l & 31;
  int qtile = blockIdx.x, sp = blockIdx.y, bh = blockIdx.z;
  int chunk = nkv / nsplit;
  int kvbase = sp * chunk;
  int qg = qtile * 128 + w * 32 + ql;

  const ushort_t* qp = qsrc + ((size_t)bh * nq + qg) * 64;
  short8 qf[4];
#pragma unroll
  for (int kk = 0; kk < 4; kk++) qf[kk] = *(const short8*)(qp + kk * 16 + h * 8);

  f32x16 acc0, acc1;
#pragma unroll
  for (int i = 0; i < 16; i++) { acc0[i] = 0.f; acc1[i] = 0.f; }

  // staging chunk assignment (512 x 16B per 8KB tile, 2 issues/thread)
  int c0 = w * 64 + l, c1 = c0 + 256;
  int r0 = c0 >> 3, s0 = ((c0 & 7) ^ (r0 & 7)) << 3;
  int r1 = c1 >> 3, s1 = ((c1 & 7) ^ (r1 & 7)) << 3;
  const ushort_t* kb = ksrc + (size_t)bh * nkv * 64;
  const ushort_t* vb = vts + (size_t)bh * 64 * vt_stride;

  float mrun = -1e30f, lrun = 0.f;
  int ntiles = chunk >> 6;
  for (int it = 0; it < ntiles; it++) {
    int kvt = kvbase + it * 64;
    __syncthreads();
    __builtin_amdgcn_global_load_lds(GPTR(kb + (size_t)(kvt + r0) * 64 + s0), LPTR(Ks + w * 512), 16, 0, 0);
    __builtin_amdgcn_global_load_lds(GPTR(kb + (size_t)(kvt + r1) * 64 + s1), LPTR(Ks + 2048 + w * 512), 16, 0, 0);
    __builtin_amdgcn_global_load_lds(GPTR(vb + (size_t)r0 * vt_stride + kvt + s0), LPTR(Vs + w * 512), 16, 0, 0);
    __builtin_amdgcn_global_load_lds(GPTR(vb + (size_t)r1 * vt_stride + kvt + s1), LPTR(Vs + 2048 + w * 512), 16, 0, 0);
    __syncthreads();

    // S^T[kv][q]: rows kv (A=K), cols q (B=Q)
    f32x16 st0, st1;
#pragma unroll
    for (int i = 0; i < 16; i++) { st0[i] = 0.f; st1[i] = 0.f; }
#pragma unroll
    for (int kk = 0; kk < 4; kk++) {
      int ch = kk * 2 + h;
      short8 kf0 = *(const short8*)(Ks + ql * 64 + ((ch ^ (ql & 7)) << 3));
      short8 kf1 = *(const short8*)(Ks + (32 + ql) * 64 + ((ch ^ (ql & 7)) << 3));
      st0 = __builtin_amdgcn_mfma_f32_32x32x16_bf16(kf0, qf[kk], st0, 0, 0, 0);
      st1 = __builtin_amdgcn_mfma_f32_32x32x16_bf16(kf1, qf[kk], st1, 0, 0, 0);
    }

    // online softmax over this 64-kv tile (per q = lane column)
    float tm = -1e30f;
#pragma unroll
    for (int r2 = 0; r2 < 16; r2++) { tm = fmaxf(tm, st0[r2]); tm = fmaxf(tm, st1[r2]); }
    tm = fmaxf(tm, __shfl_xor(tm, 32));
    float mnew = fmaxf(mrun, tm);
    float scal = __expf(mrun - mnew);
    float tsum = 0.f;
#pragma unroll
    for (int r2 = 0; r2 < 16; r2++) {
      float p0 = __expf(st0[r2] - mnew); st0[r2] = p0; tsum += p0;
      float p1 = __expf(st1[r2] - mnew); st1[r2] = p1; tsum += p1;
    }
    tsum += __shfl_xor(tsum, 32);
    lrun = lrun * scal + tsum;
    mrun = mnew;
#pragma unroll
    for (int r2 = 0; r2 < 16; r2++) { acc0[r2] *= scal; acc1[r2] *= scal; }

    // pack P -> bf16 frags (pair-swap across lane halves), then PV
#pragma unroll
    for (int nf = 0; nf < 2; nf++) {
      f32x16 stv = (nf == 0) ? st0 : st1;
      unsigned int pk[8], sw[8];
#pragma unroll
      for (int g2 = 0; g2 < 4; g2++) {
        pk[g2 * 2]     = (unsigned int)f2bf(stv[g2 * 4])     | ((unsigned int)f2bf(stv[g2 * 4 + 1]) << 16);
        pk[g2 * 2 + 1] = (unsigned int)f2bf(stv[g2 * 4 + 2]) | ((unsigned int)f2bf(stv[g2 * 4 + 3]) << 16);
      }
#pragma unroll
      for (int i2 = 0; i2 < 8; i2++) sw[i2] = (unsigned int)__shfl_xor((int)pk[i2], 32);
      union { unsigned int u[4]; short8 s; } bfr0, bfr1;
      if (h == 0) {
        bfr0.u[0] = pk[0]; bfr0.u[1] = pk[1]; bfr0.u[2] = sw[0]; bfr0.u[3] = sw[1];
        bfr1.u[0] = pk[4]; bfr1.u[1] = pk[5]; bfr1.u[2] = sw[4]; bfr1.u[3] = sw[5];
      } else {
        bfr0.u[0] = sw[2]; bfr0.u[1] = sw[3]; bfr0.u[2] = pk[2]; bfr0.u[3] = pk[3];
        bfr1.u[0] = sw[6]; bfr1.u[1] = sw[7]; bfr1.u[2] = pk[6]; bfr1.u[3] = pk[7];
      }
#pragma unroll
      for (int ks2 = 0; ks2 < 2; ks2++) {
        int ch2 = nf * 4 + ks2 * 2 + h;
        short8 vf0 = *(const short8*)(Vs + ql * 64 + ((ch2 ^ (ql & 7)) << 3));
        short8 vf1 = *(const short8*)(Vs + (32 + ql) * 64 + ((ch2 ^ (ql & 7)) << 3));
        short8 pf = ks2 ? bfr1.s : bfr0.s;
        acc0 = __builtin_amdgcn_mfma_f32_32x32x16_bf16(vf0, pf, acc0, 0, 0, 0);
        acc1 = __builtin_amdgcn_mfma_f32_32x32x16_bf16(vf1, pf, acc1, 0, 0, 0);
      }
    }
  }

  if (write_partial) {
    size_t ob = (size_t)bh * nsplit + sp;
#pragma unroll
    for (int r2 = 0; r2 < 16; r2++) {
      int row = (r2 & 3) + 8 * (r2 >> 2) + 4 * h;
      pOT[(ob * 64 + row) * nq + qg] = acc0[r2];
      pOT[(ob * 64 + 32 + row) * nq + qg] = acc1[r2];
    }
    if (h == 0) { pM[ob * nq + qg] = mrun; pL[ob * nq + qg] = lrun; }
  } else {
    float inv = 1.f / lrun;
    __syncthreads();
#pragma unroll
    for (int r2 = 0; r2 < 16; r2++) {
      int row = (r2 & 3) + 8 * (r2 >> 2) + 4 * h;
      Ot[row * 132 + w * 32 + ql] = acc0[r2] * inv;
      Ot[(32 + row) * 132 + w * 32 + ql] = acc1[r2] * inv;
    }
    __syncthreads();
    int qrow = t >> 1, half = t & 1;
    float vloc[32];
#pragma unroll
    for (int j = 0; j < 32; j++) vloc[j] = Ot[(half * 32 + j) * 132 + qrow];
    ushort_t* op = outb + ((size_t)bh * nq + qtile * 128 + qrow) * 64 + half * 32;
#pragma unroll
    for (int seg = 0; seg < 4; seg++) {
      union { ushort_t s[8]; uint4 u; } o8;
#pragma unroll
      for (int j = 0; j < 8; j++) o8.s[j] = f2bf(vloc[seg * 8 + j]);
      *(uint4*)(op + seg * 8) = o8.u;
    }
  }
}

// ------------- combine split-KV partials -> T bf16 [bh][256][64] -----------
#define NSPLIT 8
__global__ __launch_bounds__(256) void flash_combine(const float* __restrict__ pOT,
                                                     const float* __restrict__ pM,
                                                     const float* __restrict__ pL,
                                                     ushort_t* __restrict__ T, int nq) {
  int bh = blockIdx.x, qq = threadIdx.x;
  float ms[NSPLIT], ww[NSPLIT];
  float M = -1e30f;
#pragma unroll
  for (int s = 0; s < NSPLIT; s++) {
    ms[s] = pM[((size_t)bh * NSPLIT + s) * nq + qq];
    M = fmaxf(M, ms[s]);
  }
  float L = 0.f;
#pragma unroll
  for (int s = 0; s < NSPLIT; s++) {
    ww[s] = __expf(ms[s] - M);
    L += ww[s] * pL[((size_t)bh * NSPLIT + s) * nq + qq];
  }
  float invL = 1.f / L;
  ushort_t* tp = T + ((size_t)bh * nq + qq) * 64;
  for (int d0 = 0; d0 < 64; d0 += 8) {
    union { ushort_t s[8]; uint4 u; } o8;
#pragma unroll
    for (int j = 0; j < 8; j++) {
      int d = d0 + j;
      float o = 0.f;
#pragma unroll
      for (int s = 0; s < NSPLIT; s++)
        o += ww[s] * pOT[(((size_t)bh * NSPLIT + s) * 64 + d) * nq + qq];
      o8.s[j] = f2bf(o * invL);
    }
    *(uint4*)(tp + d0) = o8.u;
  }
}

// ------------- U^T = (z @ T)^T : UT[bh][64][256] ---------------------------
__global__ void zu_kernel(const float* __restrict__ z, const ushort_t* __restrict__ T,
                          ushort_t* __restrict__ UT) {
  int bh = blockIdx.y, r = blockIdx.x, d = threadIdx.x;  // 64 threads
  const float* zr = z + ((size_t)bh << 16) + ((size_t)r << 8);
  float s = 0.f;
  for (int c = 0; c < 256; c++) s = fmaf(zr[c], bf2f(T[((size_t)bh * 256 + c) * 64 + d]), s);
  UT[((size_t)bh * 64 + d) * 256 + r] = f2bf(s);
}

// ------------- depthwise residual conv over n (k=33) from vT, += outh ------
__global__ __launch_bounds__(256) void conv_vt(const ushort_t* __restrict__ vT,
                                               const float* __restrict__ wcv,
                                               ushort_t* __restrict__ outh) {
  __shared__ float vs[64][165];
  int bh = blockIdx.y, n0 = blockIdx.x * 128, t = threadIdx.x;
  int hh = bh & 7;
  {
    int r = t >> 2, part = t & 3;
    const ushort_t* src = vT + ((size_t)bh * 64 + r) * 8192;
#pragma unroll
    for (int j = 0; j < 5; j++) {
      int col = part * 40 + j * 8;
      int gn = n0 - 16 + col;
      float tmp[8];
      if (gn >= 0 && gn + 7 < 8192) {
        uint4 u = *(const uint4*)(src + gn);
        const ushort_t* us = (const ushort_t*)&u;
#pragma unroll
        for (int e = 0; e < 8; e++) tmp[e] = bf2f(us[e]);
      } else {
#pragma unroll
        for (int e = 0; e < 8; e++) {
          int g2 = gn + e;
          tmp[e] = (g2 >= 0 && g2 < 8192) ? bf2f(src[g2]) : 0.f;
        }
      }
#pragma unroll
      for (int e = 0; e < 8; e++) vs[r][col + e] = tmp[e];
    }
  }
  __syncthreads();
  int d = t & 63, ng = t >> 6;
  float win[64];
#pragma unroll
  for (int j = 0; j < 64; j++) win[j] = vs[d][ng * 32 + j];
  float o[32];
#pragma unroll
  for (int i = 0; i < 32; i++) o[i] = 0.f;
#pragma unroll
  for (int kk = 0; kk < 33; kk++) {
    float wv = wcv[hh * 33 + kk];
#pragma unroll
    for (int i = 0; i < 32; i++) o[i] = fmaf(wv, win[i + kk], o[i]);
  }
  ushort_t* op = outh + ((size_t)bh * 8192 + n0 + ng * 32) * 64 + d;
#pragma unroll
  for (int i = 0; i < 32; i++) {
    size_t oo = (size_t)i * 64;
    op[oo] = f2bf(bf2f(op[oo]) + o[i]);
  }
}

extern "C" void kernel_launch(void* const* d_in, const int* in_sizes, int n_in,
                              void* d_out, int out_size, void* d_ws, size_t ws_size,
                              hipStream_t stream) {
  (void)in_sizes; (void)n_in; (void)out_size; (void)ws_size;
  const float* x     = (const float*)d_in[0];
  const float* g     = (const float*)d_in[1];
  const float* be    = (const float*)d_in[2];
  const float* wqkv  = (const float*)d_in[3];
  const float* wout  = (const float*)d_in[4];
  const float* bout  = (const float*)d_in[5];
  const float* convw = (const float*)d_in[6];
  float* out = (float*)d_out;

  char* base = (char*)d_ws;
  size_t off = 0;
  auto alloc = [&](size_t bytes) -> void* {
    void* r = base + off; off = (off + bytes + 255) & ~(size_t)255; return r;
  };
  const size_t NBH = (size_t)32 * 8192 * 64;
  ushort_t* q     = (ushort_t*)alloc(NBH * 2);
  ushort_t* k     = (ushort_t*)alloc(NBH * 2);
  ushort_t* vT    = (ushort_t*)alloc(NBH * 2);
  ushort_t* outh  = (ushort_t*)alloc(NBH * 2);
  float*    qlf   = (float*)alloc((size_t)32 * 256 * 64 * 4);
  float*    klf   = (float*)alloc((size_t)32 * 256 * 64 * 4);
  ushort_t* qlh   = (ushort_t*)alloc((size_t)32 * 256 * 64 * 2);
  ushort_t* klh   = (ushort_t*)alloc((size_t)32 * 256 * 64 * 2);
  float*    attn2 = (float*)alloc((size_t)32 * 256 * 256 * 4);
  float*    z0    = (float*)alloc((size_t)32 * 256 * 256 * 4);
  float*    b1    = (float*)alloc((size_t)32 * 256 * 256 * 4);
  float*    b2    = (float*)alloc((size_t)32 * 256 * 256 * 4);
  float*    b3    = (float*)alloc((size_t)32 * 256 * 256 * 4);
  float*    rowsum = (float*)alloc(8192 * 4);
  float*    colsum = (float*)alloc(8192 * 4);
  float*    scl   = (float*)alloc(64);
  ushort_t* T     = (ushort_t*)alloc((size_t)32 * 256 * 64 * 2);
  ushort_t* UT    = (ushort_t*)alloc((size_t)32 * 64 * 256 * 2);
  ushort_t* Wqkvt = (ushort_t*)alloc((size_t)1536 * 512 * 2);
  ushort_t* Woutt = (ushort_t*)alloc((size_t)512 * 512 * 2);
  // ~187 MB total. Aliases: Abf (LN out) -> attn2 region (dead before sim2);
  // flash partials -> b1+b2 (pOT, exactly 16.78MB) and b3 (pM/pL), all dead
  // after the pinv loop.
  short* Abf = (short*)attn2;
  float* pOT = b1;
  float* pM  = b3;
  float* pL  = b3 + (size_t)32 * NSPLIT * 256;

  ln_bf16<<<32768, 256, 0, stream>>>(x, g, be, (ushort_t*)Abf);
  wtrans<<<dim3(8, 24), 256, 0, stream>>>(wqkv, Wqkvt, 512, 1536);
  wtrans<<<dim3(8, 8), 256, 0, stream>>>(wout, Woutt, 512, 512);
  gemm_qkv_mfma<<<dim3(256, 12), 256, 0, stream>>>(Abf, (const short*)Wqkvt, q, k, vT);
  land_kernel<<<dim3(256, 32), 64, 0, stream>>>(q, k, qlf, klf, qlh, klh);
  sim2_kernel<<<dim3(256, 32), 256, 0, stream>>>(qlf, klf, attn2);
  abssum_kernel<<<32, 256, 0, stream>>>(attn2, rowsum, colsum);
  pinv_scale_kernel<<<1, 256, 0, stream>>>(rowsum, colsum, scl);
  zinit_kernel<<<dim3(256, 32), 256, 0, stream>>>(attn2, scl, z0);

  float* pz = z0; float* pA = b1; float* pB = b2; float* pD = b3;
  for (int it = 0; it < 6; it++) {
    bmm256_kernel<<<dim3(16, 32), 256, 0, stream>>>(attn2, pz, pA, 1.f, 0.f);
    iminus_kernel<<<8192, 256, 0, stream>>>(pA, pB, 7.f);
    bmm256_kernel<<<dim3(16, 32), 256, 0, stream>>>(pA, pB, pD, -1.f, 15.f);
    bmm256_kernel<<<dim3(16, 32), 256, 0, stream>>>(pA, pD, pB, -1.f, 13.f);
    bmm256_kernel<<<dim3(16, 32), 256, 0, stream>>>(pz, pB, pD, 0.25f, 0.f);
    std::swap(pz, pD);
  }
  // pz == z0 after 6 swaps; b1..b3 now dead -> reused as flash partials.

  // T = softmax(q_land @ k^T) @ v   (split-KV 8, partials f32)
  flash_mfma<<<dim3(2, 8, 32), 256, 0, stream>>>(qlh, k, vT, T, pOT, pM, pL,
                                                 256, 8192, 8192, 8, 1);
  flash_combine<<<32, 256, 0, stream>>>(pOT, pM, pL, T, 256);
  // UT = (z @ T)^T
  zu_kernel<<<dim3(256, 32), 64, 0, stream>>>(pz, T, UT);
  // outh = softmax(q @ k_land^T) @ U
  flash_mfma<<<dim3(64, 1, 32), 256, 0, stream>>>(q, klh, UT, outh, pOT, pM, pL,
                                                  8192, 256, 256, 1, 0);
  // outh += depthwise conv residual of v
  conv_vt<<<dim3(64, 32), 256, 0, stream>>>(vT, convw, outh);
  // d_out = x + concat_heads(outh) @ w_out + b_out
  gemm_out_mfma<<<dim3(256, 4), 256, 0, stream>>>(outh, (const short*)Woutt, x, bout, out);
}

// Round 5
// 892.982 us; speedup vs baseline: 4.5323x; 1.3391x over previous
//
#include <hip/hip_runtime.h>
#include <hip/hip_bf16.h>
#include <utility>

// Shapes: b=4, n=8192, d=512, h=8, dh=64, m=256 landmarks, l=32, conv k=33. bh=32.
// Round 5: Newton-Schulz pinv loop -> split-precision (hi/lo bf16) MFMA GEMMs.
// Per iter: A=x@z ; D=A@A-7A+15I ; F=13I-A@D ; z'=0.25*z@F (4 launches, no iminus).

typedef unsigned short ushort_t;
typedef __attribute__((ext_vector_type(8))) short short8;
typedef __attribute__((ext_vector_type(4))) float f32x4;
typedef __attribute__((ext_vector_type(16))) float f32x16;

#define GPTR(p) ((const __attribute__((address_space(1))) void*)(p))
#define LPTR(p) ((__attribute__((address_space(3))) void*)(p))

__device__ inline float bf2f(ushort_t u) {
  union { unsigned int i; float f; } x; x.i = ((unsigned int)u) << 16; return x.f;
}
__device__ inline ushort_t f2bf(float f) {
  union { float f; unsigned int i; } x; x.f = f;
  unsigned int r = x.i + 0x7FFF + ((x.i >> 16) & 1);   // round-nearest-even
  return (ushort_t)(r >> 16);
}

// ---------------- LayerNorm -> bf16 [32768][512] ----------------
__global__ __launch_bounds__(256) void ln_bf16(const float* __restrict__ x,
                                               const float* __restrict__ g,
                                               const float* __restrict__ be,
                                               ushort_t* __restrict__ out) {
  int row = blockIdx.x; int t = threadIdx.x;
  const float* xr = x + (size_t)row * 512;
  float v0 = xr[t], v1 = xr[t + 256];
  __shared__ float rs[256], rq[256];
  rs[t] = v0 + v1; rq[t] = v0 * v0 + v1 * v1;
  __syncthreads();
  for (int off = 128; off > 0; off >>= 1) {
    if (t < off) { rs[t] += rs[t + off]; rq[t] += rq[t + off]; }
    __syncthreads();
  }
  float mu = rs[0] * (1.f / 512.f);
  float var = rq[0] * (1.f / 512.f) - mu * mu;
  float rstd = rsqrtf(var + 1e-5f);
  ushort_t* orow = out + (size_t)row * 512;
  orow[t]       = f2bf((v0 - mu) * rstd * g[t]       + be[t]);
  orow[t + 256] = f2bf((v1 - mu) * rstd * g[t + 256] + be[t + 256]);
}

// ------------- weight transpose+convert: in [K][N] f32 -> out [N][K] bf16 ---
__global__ __launch_bounds__(256) void wtrans(const float* __restrict__ in,
                                              ushort_t* __restrict__ outw,
                                              int K, int N) {
  __shared__ float tile[64][65];
  int kb = blockIdx.x * 64, nb = blockIdx.y * 64, t = threadIdx.x;
  for (int i = t; i < 4096; i += 256) {
    int r = i >> 6, c = i & 63;
    tile[r][c] = in[(size_t)(kb + r) * N + nb + c];
  }
  __syncthreads();
  for (int i = t; i < 4096; i += 256) {
    int r = i >> 6, c = i & 63;
    outw[(size_t)(nb + r) * K + kb + c] = f2bf(tile[c][r]);
  }
}

// ------------- MFMA GEMM: [32768,512](bf16) @ Wt[1536,512]^T -> q/k/vT ------
__global__ __launch_bounds__(256) void gemm_qkv_mfma(const short* __restrict__ Abf,
                                                     const short* __restrict__ Wt,
                                                     ushort_t* __restrict__ q,
                                                     ushort_t* __restrict__ k,
                                                     ushort_t* __restrict__ vT) {
  int bm0 = blockIdx.x * 128, bn0 = blockIdx.y * 128;
  __shared__ __align__(16) short As[128 * 32];
  __shared__ __align__(16) short Bs[128 * 32];
  int t = threadIdx.x, l = t & 63, w = t >> 6;
  int wr = w >> 1, wc = w & 1;
  int arow = w * 32 + (l >> 2);
  int akoff = (l & 3) * 8;
  const short* ag = Abf + (size_t)(bm0 + arow) * 512 + akoff;
  const short* bg = Wt + (size_t)(bn0 + arow) * 512 + akoff;
  short* Adst = As + w * 1024;
  short* Bdst = Bs + w * 1024;
  int lr = l & 15, lk = (l >> 4) * 8;
  const short* Ard = As + (wr * 64 + lr) * 32 + lk;
  const short* Brd = Bs + (wc * 64 + lr) * 32 + lk;
  f32x4 acc[16];
#pragma unroll
  for (int i = 0; i < 16; i++) acc[i] = (f32x4){0.f, 0.f, 0.f, 0.f};
  for (int k0 = 0; k0 < 512; k0 += 32) {
    __builtin_amdgcn_global_load_lds(GPTR(ag + k0), LPTR(Adst), 16, 0, 0);
    __builtin_amdgcn_global_load_lds(GPTR(ag + k0 + 16 * 512), LPTR(Adst + 512), 16, 0, 0);
    __builtin_amdgcn_global_load_lds(GPTR(bg + k0), LPTR(Bdst), 16, 0, 0);
    __builtin_amdgcn_global_load_lds(GPTR(bg + k0 + 16 * 512), LPTR(Bdst + 512), 16, 0, 0);
    __syncthreads();
    short8 af[4], bf[4];
#pragma unroll
    for (int mf = 0; mf < 4; mf++) af[mf] = *(const short8*)(Ard + mf * 512);
#pragma unroll
    for (int nf = 0; nf < 4; nf++) bf[nf] = *(const short8*)(Brd + nf * 512);
#pragma unroll
    for (int mf = 0; mf < 4; mf++)
#pragma unroll
      for (int nf = 0; nf < 4; nf++)
        acc[mf * 4 + nf] = __builtin_amdgcn_mfma_f32_16x16x32_bf16(af[mf], bf[nf], acc[mf * 4 + nf], 0, 0, 0);
    __syncthreads();
  }
#pragma unroll
  for (int mf = 0; mf < 4; mf++)
#pragma unroll
    for (int nf = 0; nf < 4; nf++) {
      int gn = bn0 + wc * 64 + nf * 16 + (l & 15);
      int part = gn >> 9, head = (gn >> 6) & 7, d = gn & 63;
      int rbase = bm0 + wr * 64 + mf * 16 + ((l >> 4) << 2);
      int bhead = (rbase >> 13) * 8 + head;
      if (part == 2) {
        union { ushort_t s[4]; unsigned long long u; } p4;
#pragma unroll
        for (int i = 0; i < 4; i++) p4.s[i] = f2bf(acc[mf * 4 + nf][i]);
        *(unsigned long long*)(vT + ((size_t)bhead * 64 + d) * 8192 + (rbase & 8191)) = p4.u;
      } else {
#pragma unroll
        for (int i = 0; i < 4; i++) {
          int gm = rbase + i;
          size_t dst = ((size_t)bhead * 8192 + (gm & 8191)) * 64 + d;
          float val = acc[mf * 4 + nf][i];
          if (part == 0) q[dst] = f2bf(val * 0.125f);
          else k[dst] = f2bf(val);
        }
      }
    }
}

// ------------- MFMA GEMM: gather(outh)[32768,512] @ Woutt^T + x + b -> out --
__global__ __launch_bounds__(256) void gemm_out_mfma(const ushort_t* __restrict__ outh,
                                                     const short* __restrict__ Wt,
                                                     const float* __restrict__ x,
                                                     const float* __restrict__ bo,
                                                     float* __restrict__ out) {
  int bm0 = blockIdx.x * 128, bn0 = blockIdx.y * 128;
  __shared__ __align__(16) short As[128 * 32];
  __shared__ __align__(16) short Bs[128 * 32];
  int t = threadIdx.x, l = t & 63, w = t >> 6;
  int wr = w >> 1, wc = w & 1;
  int arow = w * 32 + (l >> 2);
  int akoff = (l & 3) * 8;
  int gm0 = bm0 + arow, gm1 = gm0 + 16;
  const short* bg = Wt + (size_t)(bn0 + arow) * 512 + akoff;
  short* Adst = As + w * 1024;
  short* Bdst = Bs + w * 1024;
  int lr = l & 15, lk = (l >> 4) * 8;
  const short* Ard = As + (wr * 64 + lr) * 32 + lk;
  const short* Brd = Bs + (wc * 64 + lr) * 32 + lk;
  f32x4 acc[16];
#pragma unroll
  for (int i = 0; i < 16; i++) acc[i] = (f32x4){0.f, 0.f, 0.f, 0.f};
  for (int k0 = 0; k0 < 512; k0 += 32) {
    int kk = k0 + akoff;
    const ushort_t* a0 = outh + ((size_t)((gm0 >> 13) * 8 + (kk >> 6)) * 8192 + (gm0 & 8191)) * 64 + (kk & 63);
    const ushort_t* a1 = outh + ((size_t)((gm1 >> 13) * 8 + (kk >> 6)) * 8192 + (gm1 & 8191)) * 64 + (kk & 63);
    __builtin_amdgcn_global_load_lds(GPTR(a0), LPTR(Adst), 16, 0, 0);
    __builtin_amdgcn_global_load_lds(GPTR(a1), LPTR(Adst + 512), 16, 0, 0);
    __builtin_amdgcn_global_load_lds(GPTR(bg + k0), LPTR(Bdst), 16, 0, 0);
    __builtin_amdgcn_global_load_lds(GPTR(bg + k0 + 16 * 512), LPTR(Bdst + 512), 16, 0, 0);
    __syncthreads();
    short8 af[4], bf[4];
#pragma unroll
    for (int mf = 0; mf < 4; mf++) af[mf] = *(const short8*)(Ard + mf * 512);
#pragma unroll
    for (int nf = 0; nf < 4; nf++) bf[nf] = *(const short8*)(Brd + nf * 512);
#pragma unroll
    for (int mf = 0; mf < 4; mf++)
#pragma unroll
      for (int nf = 0; nf < 4; nf++)
        acc[mf * 4 + nf] = __builtin_amdgcn_mfma_f32_16x16x32_bf16(af[mf], bf[nf], acc[mf * 4 + nf], 0, 0, 0);
    __syncthreads();
  }
#pragma unroll
  for (int mf = 0; mf < 4; mf++)
#pragma unroll
    for (int nf = 0; nf < 4; nf++) {
      int gn = bn0 + wc * 64 + nf * 16 + (l & 15);
      int rbase = bm0 + wr * 64 + mf * 16 + ((l >> 4) << 2);
#pragma unroll
      for (int i = 0; i < 4; i++) {
        int gm = rbase + i;
        size_t o = (size_t)gm * 512 + gn;
        out[o] = x[o] + bo[gn] + acc[mf * 4 + nf][i];
      }
    }
}

// --------- landmarks: mean over 32 rows; fp32 (for sim2) + bf16 copies ------
__global__ void land_kernel(const ushort_t* __restrict__ q, const ushort_t* __restrict__ k,
                            float* __restrict__ qlf, float* __restrict__ klf,
                            ushort_t* __restrict__ qlh, ushort_t* __restrict__ klh) {
  int bh = blockIdx.y, mi = blockIdx.x, d = threadIdx.x;  // 64 threads
  size_t base = ((size_t)bh * 8192 + (size_t)mi * 32) * 64 + d;
  float sq = 0.f, sk = 0.f;
  for (int j = 0; j < 32; j++) {
    sq += bf2f(q[base + (size_t)j * 64]);
    sk += bf2f(k[base + (size_t)j * 64]);
  }
  size_t o = ((size_t)bh * 256 + mi) * 64 + d;
  float aq = sq * (1.f / 32.f), ak = sk * (1.f / 32.f);
  qlf[o] = aq; klf[o] = ak;
  qlh[o] = f2bf(aq); klh[o] = f2bf(ak);
}

// --------- sim2 + softmax -> x (attn2) as hi/lo bf16 [32][256][256] ---------
__global__ __launch_bounds__(256) void sim2_kernel(const float* __restrict__ ql,
                                                   const float* __restrict__ kl,
                                                   ushort_t* __restrict__ xh,
                                                   ushort_t* __restrict__ xl) {
  int bh = blockIdx.y, row = blockIdx.x, t = threadIdx.x;
  __shared__ float qrow[64];
  __shared__ float red[256];
  if (t < 64) qrow[t] = ql[((size_t)bh * 256 + row) * 64 + t];
  __syncthreads();
  const float* kr = kl + ((size_t)bh * 256 + t) * 64;
  float s = 0.f;
#pragma unroll
  for (int kd = 0; kd < 64; kd++) s = fmaf(qrow[kd], kr[kd], s);
  red[t] = s; __syncthreads();
  for (int off = 128; off > 0; off >>= 1) { if (t < off) red[t] = fmaxf(red[t], red[t + off]); __syncthreads(); }
  float mx = red[0]; __syncthreads();
  float pv = __expf(s - mx);
  red[t] = pv; __syncthreads();
  for (int off = 128; off > 0; off >>= 1) { if (t < off) red[t] += red[t + off]; __syncthreads(); }
  float pn = pv / red[0];
  size_t idx = ((size_t)bh << 16) + (size_t)row * 256 + t;
  ushort_t hi = f2bf(pn);
  xh[idx] = hi;
  xl[idx] = f2bf(pn - bf2f(hi));
}

// ------------- pinv init: abs row/col sums from hi/lo ----------------------
__global__ __launch_bounds__(256) void abssum_kernel(const ushort_t* __restrict__ xh,
                                                     const ushort_t* __restrict__ xl,
                                                     float* __restrict__ rowsum,
                                                     float* __restrict__ colsum) {
  int bh = blockIdx.x, t = threadIdx.x;
  size_t off = (size_t)bh << 16;
  float s = 0.f;
  for (int c = 0; c < 256; c++) {
    size_t i = off + (size_t)t * 256 + c;
    s += fabsf(bf2f(xh[i]) + bf2f(xl[i]));
  }
  rowsum[bh * 256 + t] = s;
  float s2 = 0.f;
  for (int r = 0; r < 256; r++) {
    size_t i = off + (size_t)r * 256 + t;
    s2 += fabsf(bf2f(xh[i]) + bf2f(xl[i]));
  }
  colsum[bh * 256 + t] = s2;
}

__global__ __launch_bounds__(256) void pinv_scale_kernel(const float* __restrict__ rowsum,
                                                         const float* __restrict__ colsum,
                                                         float* __restrict__ scl) {
  int t = threadIdx.x;
  float m1 = 0.f, m2 = 0.f;
  for (int i = t; i < 8192; i += 256) { m1 = fmaxf(m1, rowsum[i]); m2 = fmaxf(m2, colsum[i]); }
  __shared__ float r1[256], r2[256];
  r1[t] = m1; r2[t] = m2; __syncthreads();
  for (int off = 128; off > 0; off >>= 1) {
    if (t < off) { r1[t] = fmaxf(r1[t], r1[t + off]); r2[t] = fmaxf(r2[t], r2[t + off]); }
    __syncthreads();
  }
  if (t == 0) scl[0] = 1.f / (r1[0] * r2[0]);
}

// ------------- z0 = x^T*s (row hi/lo) and z0^T = x*s (hi/lo) ---------------
__global__ __launch_bounds__(256) void zinit_kernel(const ushort_t* __restrict__ xh,
                                                    const ushort_t* __restrict__ xl,
                                                    const float* __restrict__ scl,
                                                    ushort_t* __restrict__ zrh,
                                                    ushort_t* __restrict__ zrl,
                                                    ushort_t* __restrict__ zth,
                                                    ushort_t* __restrict__ ztl) {
  int bh = blockIdx.y, i = blockIdx.x, j = threadIdx.x;
  size_t off = (size_t)bh << 16;
  float s = scl[0];
  // z0[i][j] = x[j][i]*s  (column read)
  size_t src1 = off + (size_t)j * 256 + i;
  float v1 = (bf2f(xh[src1]) + bf2f(xl[src1])) * s;
  size_t dst = off + (size_t)i * 256 + j;
  ushort_t h1 = f2bf(v1);
  zrh[dst] = h1; zrl[dst] = f2bf(v1 - bf2f(h1));
  // z0T[i][j] = x[i][j]*s  (row read)
  size_t src2 = off + (size_t)i * 256 + j;
  float v2 = (bf2f(xh[src2]) + bf2f(xl[src2])) * s;
  ushort_t h2 = f2bf(v2);
  zth[dst] = h2; ztl[dst] = f2bf(v2 - bf2f(h2));
}

// ------- NS split-precision MFMA GEMM on [32][256][256] hi/lo bf16 ---------
// C = A @ B, A stored as rows [256][256] (hi/lo); B stored as B^T rows (hi/lo).
// MODE 0: E=acc;                 write C rows + C^T        (A = x@z)
// MODE 1: E=acc-7*Ex+15I;        write C^T only            (D = A@A-7A+15I)
// MODE 2: E=13I-acc;             write C^T only            (F = 13I-A@D)
// MODE 3: E=0.25*acc;            write C rows + C^T        (z' = 0.25*z@F)
template<int MODE>
__global__ __launch_bounds__(256) void bmm_ns(
    const ushort_t* __restrict__ Agh, const ushort_t* __restrict__ Agl,
    const ushort_t* __restrict__ Bgh, const ushort_t* __restrict__ Bgl,
    const ushort_t* __restrict__ Exh, const ushort_t* __restrict__ Exl,
    ushort_t* __restrict__ C1h, ushort_t* __restrict__ C1l,
    ushort_t* __restrict__ C2h, ushort_t* __restrict__ C2l) {
  __shared__ __align__(16) ushort_t Ahs[4096], Bhs[4096], Als[4096], Bls[4096];
  int t = threadIdx.x, l = t & 63, w = t >> 6, h = l >> 5;
  int tile = blockIdx.x, bh = blockIdx.y;
  int tr = (tile >> 2) << 6, tc = (tile & 3) << 6;
  size_t off = (size_t)bh << 16;

  // staging indices (both issues), source pre-swizzled for linear LDS dst
  int id0 = w * 64 + l, id1 = id0 + 256;
  int r0 = id0 >> 3, cs0 = (id0 & 7) ^ (r0 & 7);
  int r1 = id1 >> 3, cs1 = (id1 & 7) ^ (r1 & 7);

  f32x16 acc;
#pragma unroll
  for (int i = 0; i < 16; i++) acc[i] = 0.f;

  int rA = ((w >> 1) << 5) + (l & 31);
  int rB = ((w & 1) << 5) + (l & 31);
  int baA = rA << 7, baB = rB << 7;   // byte row bases (128B rows)

  for (int s = 0; s < 4; s++) {
    int k0 = s << 6;
    if (s) __syncthreads();
    {
      const ushort_t* a0 = Agh + off + (size_t)(tr + r0) * 256 + k0 + cs0 * 8;
      const ushort_t* a1 = Agh + off + (size_t)(tr + r1) * 256 + k0 + cs1 * 8;
      const ushort_t* b0 = Bgh + off + (size_t)(tc + r0) * 256 + k0 + cs0 * 8;
      const ushort_t* b1 = Bgh + off + (size_t)(tc + r1) * 256 + k0 + cs1 * 8;
      __builtin_amdgcn_global_load_lds(GPTR(a0), LPTR((char*)Ahs + w * 1024), 16, 0, 0);
      __builtin_amdgcn_global_load_lds(GPTR(a1), LPTR((char*)Ahs + w * 1024 + 4096), 16, 0, 0);
      __builtin_amdgcn_global_load_lds(GPTR(b0), LPTR((char*)Bhs + w * 1024), 16, 0, 0);
      __builtin_amdgcn_global_load_lds(GPTR(b1), LPTR((char*)Bhs + w * 1024 + 4096), 16, 0, 0);
      const ushort_t* a2 = Agl + off + (size_t)(tr + r0) * 256 + k0 + cs0 * 8;
      const ushort_t* a3 = Agl + off + (size_t)(tr + r1) * 256 + k0 + cs1 * 8;
      const ushort_t* b2 = Bgl + off + (size_t)(tc + r0) * 256 + k0 + cs0 * 8;
      const ushort_t* b3 = Bgl + off + (size_t)(tc + r1) * 256 + k0 + cs1 * 8;
      __builtin_amdgcn_global_load_lds(GPTR(a2), LPTR((char*)Als + w * 1024), 16, 0, 0);
      __builtin_amdgcn_global_load_lds(GPTR(a3), LPTR((char*)Als + w * 1024 + 4096), 16, 0, 0);
      __builtin_amdgcn_global_load_lds(GPTR(b2), LPTR((char*)Bls + w * 1024), 16, 0, 0);
      __builtin_amdgcn_global_load_lds(GPTR(b3), LPTR((char*)Bls + w * 1024 + 4096), 16, 0, 0);
    }
    __syncthreads();
#pragma unroll
    for (int kk = 0; kk < 4; kk++) {
      int swA = (((kk << 1) + h) ^ (rA & 7)) << 4;
      int swB = (((kk << 1) + h) ^ (rB & 7)) << 4;
      short8 afh = *(const short8*)((const char*)Ahs + baA + swA);
      short8 bfh = *(const short8*)((const char*)Bhs + baB + swB);
      short8 afl = *(const short8*)((const char*)Als + baA + swA);
      short8 bfl = *(const short8*)((const char*)Bls + baB + swB);
      acc = __builtin_amdgcn_mfma_f32_32x32x16_bf16(afh, bfh, acc, 0, 0, 0);
      acc = __builtin_amdgcn_mfma_f32_32x32x16_bf16(afh, bfl, acc, 0, 0, 0);
      acc = __builtin_amdgcn_mfma_f32_32x32x16_bf16(afl, bfh, acc, 0, 0, 0);
    }
  }

  int qr = tr + ((w >> 1) << 5), qc = tc + ((w & 1) << 5);
  int gn = qc + (l & 31);
#pragma unroll
  for (int reg = 0; reg < 16; reg++) {
    int m = (reg & 3) + ((reg >> 2) << 3) + (h << 2);
    int gm = qr + m;
    float e = acc[reg];
    if (MODE == 1) {
      size_t ei = off + (size_t)gm * 256 + gn;
      e = e - 7.f * (bf2f(Exh[ei]) + bf2f(Exl[ei])) + (gm == gn ? 15.f : 0.f);
    } else if (MODE == 2) {
      e = (gm == gn ? 13.f : 0.f) - e;
    } else if (MODE == 3) {
      e *= 0.25f;
    }
    ushort_t hi = f2bf(e);
    ushort_t lo = f2bf(e - bf2f(hi));
    if (MODE == 0 || MODE == 3) {
      size_t d1 = off + (size_t)gm * 256 + gn;
      C1h[d1] = hi; C1l[d1] = lo;
    }
    size_t d2 = off + (size_t)gn * 256 + gm;
    C2h[d2] = hi; C2l[d2] = lo;
  }
}

// ------------- MFMA flash: out = softmax(qsrc @ ksrc^T) @ V ----------------
__global__ __launch_bounds__(256) void flash_mfma(
    const ushort_t* __restrict__ qsrc, const ushort_t* __restrict__ ksrc,
    const ushort_t* __restrict__ vts, ushort_t* __restrict__ outb,
    float* __restrict__ pOT, float* __restrict__ pM, float* __restrict__ pL,
    int nq, int nkv, int vt_stride, int nsplit, int write_partial) {
  __shared__ __align__(16) char smem[64 * 132 * 4];
  ushort_t* Ks = (ushort_t*)smem;
  ushort_t* Vs = (ushort_t*)(smem + 8192);
  float* Ot = (float*)smem;

  int t = threadIdx.x, l = t & 63, w = t >> 6, h = l >> 5, ql = l & 31;
  int qtile = blockIdx.x, sp = blockIdx.y, bh = blockIdx.z;
  int chunk = nkv / nsplit;
  int kvbase = sp * chunk;
  int qg = qtile * 128 + w * 32 + ql;

  const ushort_t* qp = qsrc + ((size_t)bh * nq + qg) * 64;
  short8 qf[4];
#pragma unroll
  for (int kk = 0; kk < 4; kk++) qf[kk] = *(const short8*)(qp + kk * 16 + h * 8);

  f32x16 acc0, acc1;
#pragma unroll
  for (int i = 0; i < 16; i++) { acc0[i] = 0.f; acc1[i] = 0.f; }

  int c0 = w * 64 + l, c1 = c0 + 256;
  int r0 = c0 >> 3, s0 = ((c0 & 7) ^ (r0 & 7)) << 3;
  int r1 = c1 >> 3, s1 = ((c1 & 7) ^ (r1 & 7)) << 3;
  const ushort_t* kb = ksrc + (size_t)bh * nkv * 64;
  const ushort_t* vb = vts + (size_t)bh * 64 * vt_stride;

  float mrun = -1e30f, lrun = 0.f;
  int ntiles = chunk >> 6;
  for (int it = 0; it < ntiles; it++) {
    int kvt = kvbase + it * 64;
    __syncthreads();
    __builtin_amdgcn_global_load_lds(GPTR(kb + (size_t)(kvt + r0) * 64 + s0), LPTR(Ks + w * 512), 16, 0, 0);
    __builtin_amdgcn_global_load_lds(GPTR(kb + (size_t)(kvt + r1) * 64 + s1), LPTR(Ks + 2048 + w * 512), 16, 0, 0);
    __builtin_amdgcn_global_load_lds(GPTR(vb + (size_t)r0 * vt_stride + kvt + s0), LPTR(Vs + w * 512), 16, 0, 0);
    __builtin_amdgcn_global_load_lds(GPTR(vb + (size_t)r1 * vt_stride + kvt + s1), LPTR(Vs + 2048 + w * 512), 16, 0, 0);
    __syncthreads();

    f32x16 st0, st1;
#pragma unroll
    for (int i = 0; i < 16; i++) { st0[i] = 0.f; st1[i] = 0.f; }
#pragma unroll
    for (int kk = 0; kk < 4; kk++) {
      int ch = kk * 2 + h;
      short8 kf0 = *(const short8*)(Ks + ql * 64 + ((ch ^ (ql & 7)) << 3));
      short8 kf1 = *(const short8*)(Ks + (32 + ql) * 64 + ((ch ^ (ql & 7)) << 3));
      st0 = __builtin_amdgcn_mfma_f32_32x32x16_bf16(kf0, qf[kk], st0, 0, 0, 0);
      st1 = __builtin_amdgcn_mfma_f32_32x32x16_bf16(kf1, qf[kk], st1, 0, 0, 0);
    }

    float tm = -1e30f;
#pragma unroll
    for (int r2 = 0; r2 < 16; r2++) { tm = fmaxf(tm, st0[r2]); tm = fmaxf(tm, st1[r2]); }
    tm = fmaxf(tm, __shfl_xor(tm, 32));
    float mnew = fmaxf(mrun, tm);
    float scal = __expf(mrun - mnew);
    float tsum = 0.f;
#pragma unroll
    for (int r2 = 0; r2 < 16; r2++) {
      float p0 = __expf(st0[r2] - mnew); st0[r2] = p0; tsum += p0;
      float p1 = __expf(st1[r2] - mnew); st1[r2] = p1; tsum += p1;
    }
    tsum += __shfl_xor(tsum, 32);
    lrun = lrun * scal + tsum;
    mrun = mnew;
#pragma unroll
    for (int r2 = 0; r2 < 16; r2++) { acc0[r2] *= scal; acc1[r2] *= scal; }

#pragma unroll
    for (int nf = 0; nf < 2; nf++) {
      f32x16 stv = (nf == 0) ? st0 : st1;
      unsigned int pk[8], sw[8];
#pragma unroll
      for (int g2 = 0; g2 < 4; g2++) {
        pk[g2 * 2]     = (unsigned int)f2bf(stv[g2 * 4])     | ((unsigned int)f2bf(stv[g2 * 4 + 1]) << 16);
        pk[g2 * 2 + 1] = (unsigned int)f2bf(stv[g2 * 4 + 2]) | ((unsigned int)f2bf(stv[g2 * 4 + 3]) << 16);
      }
#pragma unroll
      for (int i2 = 0; i2 < 8; i2++) sw[i2] = (unsigned int)__shfl_xor((int)pk[i2], 32);
      union { unsigned int u[4]; short8 s; } bfr0, bfr1;
      if (h == 0) {
        bfr0.u[0] = pk[0]; bfr0.u[1] = pk[1]; bfr0.u[2] = sw[0]; bfr0.u[3] = sw[1];
        bfr1.u[0] = pk[4]; bfr1.u[1] = pk[5]; bfr1.u[2] = sw[4]; bfr1.u[3] = sw[5];
      } else {
        bfr0.u[0] = sw[2]; bfr0.u[1] = sw[3]; bfr0.u[2] = pk[2]; bfr0.u[3] = pk[3];
        bfr1.u[0] = sw[6]; bfr1.u[1] = sw[7]; bfr1.u[2] = pk[6]; bfr1.u[3] = pk[7];
      }
#pragma unroll
      for (int ks2 = 0; ks2 < 2; ks2++) {
        int ch2 = nf * 4 + ks2 * 2 + h;
        short8 vf0 = *(const short8*)(Vs + ql * 64 + ((ch2 ^ (ql & 7)) << 3));
        short8 vf1 = *(const short8*)(Vs + (32 + ql) * 64 + ((ch2 ^ (ql & 7)) << 3));
        short8 pf = ks2 ? bfr1.s : bfr0.s;
        acc0 = __builtin_amdgcn_mfma_f32_32x32x16_bf16(vf0, pf, acc0, 0, 0, 0);
        acc1 = __builtin_amdgcn_mfma_f32_32x32x16_bf16(vf1, pf, acc1, 0, 0, 0);
      }
    }
  }

  if (write_partial) {
    size_t ob = (size_t)bh * nsplit + sp;
#pragma unroll
    for (int r2 = 0; r2 < 16; r2++) {
      int row = (r2 & 3) + 8 * (r2 >> 2) + 4 * h;
      pOT[(ob * 64 + row) * nq + qg] = acc0[r2];
      pOT[(ob * 64 + 32 + row) * nq + qg] = acc1[r2];
    }
    if (h == 0) { pM[ob * nq + qg] = mrun; pL[ob * nq + qg] = lrun; }
  } else {
    float inv = 1.f / lrun;
    __syncthreads();
#pragma unroll
    for (int r2 = 0; r2 < 16; r2++) {
      int row = (r2 & 3) + 8 * (r2 >> 2) + 4 * h;
      Ot[row * 132 + w * 32 + ql] = acc0[r2] * inv;
      Ot[(32 + row) * 132 + w * 32 + ql] = acc1[r2] * inv;
    }
    __syncthreads();
    int qrow = t >> 1, half = t & 1;
    float vloc[32];
#pragma unroll
    for (int j = 0; j < 32; j++) vloc[j] = Ot[(half * 32 + j) * 132 + qrow];
    ushort_t* op = outb + ((size_t)bh * nq + qtile * 128 + qrow) * 64 + half * 32;
#pragma unroll
    for (int seg = 0; seg < 4; seg++) {
      union { ushort_t s[8]; uint4 u; } o8;
#pragma unroll
      for (int j = 0; j < 8; j++) o8.s[j] = f2bf(vloc[seg * 8 + j]);
      *(uint4*)(op + seg * 8) = o8.u;
    }
  }
}

// ------------- combine split-KV partials -> T bf16 [bh][256][64] -----------
#define NSPLIT 8
__global__ __launch_bounds__(256) void flash_combine(const float* __restrict__ pOT,
                                                     const float* __restrict__ pM,
                                                     const float* __restrict__ pL,
                                                     ushort_t* __restrict__ T, int nq) {
  int bh = blockIdx.x, qq = threadIdx.x;
  float ms[NSPLIT], ww[NSPLIT];
  float M = -1e30f;
#pragma unroll
  for (int s = 0; s < NSPLIT; s++) {
    ms[s] = pM[((size_t)bh * NSPLIT + s) * nq + qq];
    M = fmaxf(M, ms[s]);
  }
  float L = 0.f;
#pragma unroll
  for (int s = 0; s < NSPLIT; s++) {
    ww[s] = __expf(ms[s] - M);
    L += ww[s] * pL[((size_t)bh * NSPLIT + s) * nq + qq];
  }
  float invL = 1.f / L;
  ushort_t* tp = T + ((size_t)bh * nq + qq) * 64;
  for (int d0 = 0; d0 < 64; d0 += 8) {
    union { ushort_t s[8]; uint4 u; } o8;
#pragma unroll
    for (int j = 0; j < 8; j++) {
      int d = d0 + j;
      float o = 0.f;
#pragma unroll
      for (int s = 0; s < NSPLIT; s++)
        o += ww[s] * pOT[(((size_t)bh * NSPLIT + s) * 64 + d) * nq + qq];
      o8.s[j] = f2bf(o * invL);
    }
    *(uint4*)(tp + d0) = o8.u;
  }
}

// ------------- U^T = (z @ T)^T : UT[bh][64][256], z from hi/lo --------------
__global__ void zu_kernel(const ushort_t* __restrict__ zh, const ushort_t* __restrict__ zl,
                          const ushort_t* __restrict__ T, ushort_t* __restrict__ UT) {
  int bh = blockIdx.y, r = blockIdx.x, d = threadIdx.x;  // 64 threads
  size_t zoff = ((size_t)bh << 16) + ((size_t)r << 8);
  float s = 0.f;
  for (int c = 0; c < 256; c++) {
    float zv = bf2f(zh[zoff + c]) + bf2f(zl[zoff + c]);
    s = fmaf(zv, bf2f(T[((size_t)bh * 256 + c) * 64 + d]), s);
  }
  UT[((size_t)bh * 64 + d) * 256 + r] = f2bf(s);
}

// ------------- depthwise residual conv over n (k=33) from vT, += outh ------
__global__ __launch_bounds__(256) void conv_vt(const ushort_t* __restrict__ vT,
                                               const float* __restrict__ wcv,
                                               ushort_t* __restrict__ outh) {
  __shared__ float vs[64][165];
  int bh = blockIdx.y, n0 = blockIdx.x * 128, t = threadIdx.x;
  int hh = bh & 7;
  {
    int r = t >> 2, part = t & 3;
    const ushort_t* src = vT + ((size_t)bh * 64 + r) * 8192;
#pragma unroll
    for (int j = 0; j < 5; j++) {
      int col = part * 40 + j * 8;
      int gn = n0 - 16 + col;
      float tmp[8];
      if (gn >= 0 && gn + 7 < 8192) {
        uint4 u = *(const uint4*)(src + gn);
        const ushort_t* us = (const ushort_t*)&u;
#pragma unroll
        for (int e = 0; e < 8; e++) tmp[e] = bf2f(us[e]);
      } else {
#pragma unroll
        for (int e = 0; e < 8; e++) {
          int g2 = gn + e;
          tmp[e] = (g2 >= 0 && g2 < 8192) ? bf2f(src[g2]) : 0.f;
        }
      }
#pragma unroll
      for (int e = 0; e < 8; e++) vs[r][col + e] = tmp[e];
    }
  }
  __syncthreads();
  int d = t & 63, ng = t >> 6;
  float win[64];
#pragma unroll
  for (int j = 0; j < 64; j++) win[j] = vs[d][ng * 32 + j];
  float o[32];
#pragma unroll
  for (int i = 0; i < 32; i++) o[i] = 0.f;
#pragma unroll
  for (int kk = 0; kk < 33; kk++) {
    float wv = wcv[hh * 33 + kk];
#pragma unroll
    for (int i = 0; i < 32; i++) o[i] = fmaf(wv, win[i + kk], o[i]);
  }
  ushort_t* op = outh + ((size_t)bh * 8192 + n0 + ng * 32) * 64 + d;
#pragma unroll
  for (int i = 0; i < 32; i++) {
    size_t oo = (size_t)i * 64;
    op[oo] = f2bf(bf2f(op[oo]) + o[i]);
  }
}

extern "C" void kernel_launch(void* const* d_in, const int* in_sizes, int n_in,
                              void* d_out, int out_size, void* d_ws, size_t ws_size,
                              hipStream_t stream) {
  (void)in_sizes; (void)n_in; (void)out_size; (void)ws_size;
  const float* x     = (const float*)d_in[0];
  const float* g     = (const float*)d_in[1];
  const float* be    = (const float*)d_in[2];
  const float* wqkv  = (const float*)d_in[3];
  const float* wout  = (const float*)d_in[4];
  const float* bout  = (const float*)d_in[5];
  const float* convw = (const float*)d_in[6];
  float* out = (float*)d_out;

  char* base = (char*)d_ws;
  size_t off = 0;
  auto alloc = [&](size_t bytes) -> void* {
    void* r = base + off; off = (off + bytes + 255) & ~(size_t)255; return r;
  };
  const size_t NBH = (size_t)32 * 8192 * 64;
  const size_t M2 = (size_t)32 * 256 * 256 * 2;  // one [32][256][256] bf16 = 4 MB
  ushort_t* q     = (ushort_t*)alloc(NBH * 2);
  ushort_t* k     = (ushort_t*)alloc(NBH * 2);
  ushort_t* vT    = (ushort_t*)alloc(NBH * 2);
  ushort_t* outh  = (ushort_t*)alloc(NBH * 2);
  float*    qlf   = (float*)alloc((size_t)32 * 256 * 64 * 4);
  float*    klf   = (float*)alloc((size_t)32 * 256 * 64 * 4);
  ushort_t* qlh   = (ushort_t*)alloc((size_t)32 * 256 * 64 * 2);
  ushort_t* klh   = (ushort_t*)alloc((size_t)32 * 256 * 64 * 2);
  ushort_t* xh    = (ushort_t*)alloc(M2);
  ushort_t* xl    = (ushort_t*)alloc(M2);
  ushort_t* zArh  = (ushort_t*)alloc(M2);
  ushort_t* zArl  = (ushort_t*)alloc(M2);
  ushort_t* zAth  = (ushort_t*)alloc(M2);
  ushort_t* zAtl  = (ushort_t*)alloc(M2);
  ushort_t* zBrh  = (ushort_t*)alloc(M2);
  ushort_t* zBrl  = (ushort_t*)alloc(M2);
  ushort_t* zBth  = (ushort_t*)alloc(M2);
  ushort_t* zBtl  = (ushort_t*)alloc(M2);
  ushort_t* ARh   = (ushort_t*)alloc(M2);
  ushort_t* ARl   = (ushort_t*)alloc(M2);
  ushort_t* ATh   = (ushort_t*)alloc(M2);
  ushort_t* ATl   = (ushort_t*)alloc(M2);
  ushort_t* DTh   = (ushort_t*)alloc(M2);
  ushort_t* DTl   = (ushort_t*)alloc(M2);
  ushort_t* FTh   = (ushort_t*)alloc(M2);
  ushort_t* FTl   = (ushort_t*)alloc(M2);
  float*    rowsum = (float*)alloc(8192 * 4);
  float*    colsum = (float*)alloc(8192 * 4);
  float*    scl   = (float*)alloc(64);
  ushort_t* T     = (ushort_t*)alloc((size_t)32 * 256 * 64 * 2);
  ushort_t* UT    = (ushort_t*)alloc((size_t)32 * 64 * 256 * 2);
  ushort_t* Wqkvt = (ushort_t*)alloc((size_t)1536 * 512 * 2);
  ushort_t* Woutt = (ushort_t*)alloc((size_t)512 * 512 * 2);
  // ~220 MB. Aliases: LN output Abf -> xh..zAth region (dead before sim2);
  // flash partials -> ARh..ATl (pOT, exactly 16 MB... 4x4.19MB = 16.78MB) and
  // DTh (pM/pL), all dead after the pinv loop.
  short* Abf = (short*)xh;           // needs 33.5 MB: spans xh..zAth (4 x 4.19+ MB? no)
  // careful: Abf needs 32768*512*2 = 33.55 MB = 8 consecutive M2 arrays (xh..zBtl).
  // xh..zBtl are 10 arrays (41.9 MB), all written only later. OK.
  float* pOT = (float*)ARh;          // 16.78 MB = ARh+ARl+ATh+ATl exactly
  float* pM  = (float*)DTh;
  float* pL  = (float*)DTh + 65536;

  ln_bf16<<<32768, 256, 0, stream>>>(x, g, be, (ushort_t*)Abf);
  wtrans<<<dim3(8, 24), 256, 0, stream>>>(wqkv, Wqkvt, 512, 1536);
  wtrans<<<dim3(8, 8), 256, 0, stream>>>(wout, Woutt, 512, 512);
  gemm_qkv_mfma<<<dim3(256, 12), 256, 0, stream>>>(Abf, (const short*)Wqkvt, q, k, vT);
  land_kernel<<<dim3(256, 32), 64, 0, stream>>>(q, k, qlf, klf, qlh, klh);
  sim2_kernel<<<dim3(256, 32), 256, 0, stream>>>(qlf, klf, xh, xl);
  abssum_kernel<<<32, 256, 0, stream>>>(xh, xl, rowsum, colsum);
  pinv_scale_kernel<<<1, 256, 0, stream>>>(rowsum, colsum, scl);
  zinit_kernel<<<dim3(256, 32), 256, 0, stream>>>(xh, xl, scl, zArh, zArl, zAth, zAtl);

  ushort_t *zrh = zArh, *zrl = zArl, *zth = zAth, *ztl = zAtl;
  ushort_t *nrh = zBrh, *nrl = zBrl, *nth = zBth, *ntl = zBtl;
  dim3 nsgrid(16, 32);
  for (int it = 0; it < 6; it++) {
    bmm_ns<0><<<nsgrid, 256, 0, stream>>>(xh, xl, zth, ztl, xh, xl, ARh, ARl, ATh, ATl);
    bmm_ns<1><<<nsgrid, 256, 0, stream>>>(ARh, ARl, ATh, ATl, ARh, ARl, xh, xl, DTh, DTl);
    bmm_ns<2><<<nsgrid, 256, 0, stream>>>(ARh, ARl, DTh, DTl, xh, xl, xh, xl, FTh, FTl);
    bmm_ns<3><<<nsgrid, 256, 0, stream>>>(zrh, zrl, FTh, FTl, xh, xl, nrh, nrl, nth, ntl);
    std::swap(zrh, nrh); std::swap(zrl, nrl);
    std::swap(zth, nth); std::swap(ztl, ntl);
  }
  // after 6 swaps, final z rows = zArh/zArl (= zrh/zrl). A/D/F/x now dead.

  // T = softmax(q_land @ k^T) @ v   (split-KV 8, partials f32)
  flash_mfma<<<dim3(2, 8, 32), 256, 0, stream>>>(qlh, k, vT, T, pOT, pM, pL,
                                                 256, 8192, 8192, 8, 1);
  flash_combine<<<32, 256, 0, stream>>>(pOT, pM, pL, T, 256);
  // UT = (z @ T)^T
  zu_kernel<<<dim3(256, 32), 64, 0, stream>>>(zrh, zrl, T, UT);
  // outh = softmax(q @ k_land^T) @ U
  flash_mfma<<<dim3(64, 1, 32), 256, 0, stream>>>(q, klh, UT, outh, pOT, pM, pL,
                                                  8192, 256, 256, 1, 0);
  // outh += depthwise conv residual of v
  conv_vt<<<dim3(64, 32), 256, 0, stream>>>(vT, convw, outh);
  // d_out = x + concat_heads(outh) @ w_out + b_out
  gemm_out_mfma<<<dim3(256, 4), 256, 0, stream>>>(outh, (const short*)Woutt, x, bout, out);
}

// Round 6
// 798.277 us; speedup vs baseline: 5.0700x; 1.1186x over previous
//
#include <hip/hip_runtime.h>
#include <hip/hip_bf16.h>
#include <utility>

// Shapes: b=4, n=8192, d=512, h=8, dh=64, m=256 landmarks, l=32, conv k=33. bh=32.
// Round 6: bmm_ns -> 2-phase pipelined staging + LDS-bounce vectorized epilogue;
// zu -> LDS-tiled 256-thread kernel; ln -> wave-shuffle reduce.

typedef unsigned short ushort_t;
typedef __attribute__((ext_vector_type(8))) short short8;
typedef __attribute__((ext_vector_type(4))) float f32x4;
typedef __attribute__((ext_vector_type(16))) float f32x16;

#define GPTR(p) ((const __attribute__((address_space(1))) void*)(p))
#define LPTR(p) ((__attribute__((address_space(3))) void*)(p))

__device__ inline float bf2f(ushort_t u) {
  union { unsigned int i; float f; } x; x.i = ((unsigned int)u) << 16; return x.f;
}
__device__ inline ushort_t f2bf(float f) {
  union { float f; unsigned int i; } x; x.f = f;
  unsigned int r = x.i + 0x7FFF + ((x.i >> 16) & 1);   // round-nearest-even
  return (ushort_t)(r >> 16);
}

// ---------------- LayerNorm -> bf16 [32768][512] ----------------
__global__ __launch_bounds__(256) void ln_bf16(const float* __restrict__ x,
                                               const float* __restrict__ g,
                                               const float* __restrict__ be,
                                               ushort_t* __restrict__ out) {
  int row = blockIdx.x; int t = threadIdx.x;
  const float* xr = x + (size_t)row * 512;
  float2 v = *(const float2*)(xr + 2 * t);
  float s = v.x + v.y, qs = v.x * v.x + v.y * v.y;
#pragma unroll
  for (int o = 32; o > 0; o >>= 1) { s += __shfl_xor(s, o); qs += __shfl_xor(qs, o); }
  __shared__ float ps[4], pq[4];
  if ((t & 63) == 0) { ps[t >> 6] = s; pq[t >> 6] = qs; }
  __syncthreads();
  s = ps[0] + ps[1] + ps[2] + ps[3];
  qs = pq[0] + pq[1] + pq[2] + pq[3];
  float mu = s * (1.f / 512.f);
  float var = qs * (1.f / 512.f) - mu * mu;
  float rstd = rsqrtf(var + 1e-5f);
  float o0 = (v.x - mu) * rstd * g[2 * t] + be[2 * t];
  float o1 = (v.y - mu) * rstd * g[2 * t + 1] + be[2 * t + 1];
  unsigned int pk = (unsigned int)f2bf(o0) | ((unsigned int)f2bf(o1) << 16);
  *(unsigned int*)(out + (size_t)row * 512 + 2 * t) = pk;
}

// ------------- weight transpose+convert: in [K][N] f32 -> out [N][K] bf16 ---
__global__ __launch_bounds__(256) void wtrans(const float* __restrict__ in,
                                              ushort_t* __restrict__ outw,
                                              int K, int N) {
  __shared__ float tile[64][65];
  int kb = blockIdx.x * 64, nb = blockIdx.y * 64, t = threadIdx.x;
  for (int i = t; i < 4096; i += 256) {
    int r = i >> 6, c = i & 63;
    tile[r][c] = in[(size_t)(kb + r) * N + nb + c];
  }
  __syncthreads();
  for (int i = t; i < 4096; i += 256) {
    int r = i >> 6, c = i & 63;
    outw[(size_t)(nb + r) * K + kb + c] = f2bf(tile[c][r]);
  }
}

// ------------- MFMA GEMM: [32768,512](bf16) @ Wt[1536,512]^T -> q/k/vT ------
__global__ __launch_bounds__(256) void gemm_qkv_mfma(const short* __restrict__ Abf,
                                                     const short* __restrict__ Wt,
                                                     ushort_t* __restrict__ q,
                                                     ushort_t* __restrict__ k,
                                                     ushort_t* __restrict__ vT) {
  int bm0 = blockIdx.x * 128, bn0 = blockIdx.y * 128;
  __shared__ __align__(16) short As[128 * 32];
  __shared__ __align__(16) short Bs[128 * 32];
  int t = threadIdx.x, l = t & 63, w = t >> 6;
  int wr = w >> 1, wc = w & 1;
  int arow = w * 32 + (l >> 2);
  int akoff = (l & 3) * 8;
  const short* ag = Abf + (size_t)(bm0 + arow) * 512 + akoff;
  const short* bg = Wt + (size_t)(bn0 + arow) * 512 + akoff;
  short* Adst = As + w * 1024;
  short* Bdst = Bs + w * 1024;
  int lr = l & 15, lk = (l >> 4) * 8;
  const short* Ard = As + (wr * 64 + lr) * 32 + lk;
  const short* Brd = Bs + (wc * 64 + lr) * 32 + lk;
  f32x4 acc[16];
#pragma unroll
  for (int i = 0; i < 16; i++) acc[i] = (f32x4){0.f, 0.f, 0.f, 0.f};
  for (int k0 = 0; k0 < 512; k0 += 32) {
    __builtin_amdgcn_global_load_lds(GPTR(ag + k0), LPTR(Adst), 16, 0, 0);
    __builtin_amdgcn_global_load_lds(GPTR(ag + k0 + 16 * 512), LPTR(Adst + 512), 16, 0, 0);
    __builtin_amdgcn_global_load_lds(GPTR(bg + k0), LPTR(Bdst), 16, 0, 0);
    __builtin_amdgcn_global_load_lds(GPTR(bg + k0 + 16 * 512), LPTR(Bdst + 512), 16, 0, 0);
    __syncthreads();
    short8 af[4], bf[4];
#pragma unroll
    for (int mf = 0; mf < 4; mf++) af[mf] = *(const short8*)(Ard + mf * 512);
#pragma unroll
    for (int nf = 0; nf < 4; nf++) bf[nf] = *(const short8*)(Brd + nf * 512);
#pragma unroll
    for (int mf = 0; mf < 4; mf++)
#pragma unroll
      for (int nf = 0; nf < 4; nf++)
        acc[mf * 4 + nf] = __builtin_amdgcn_mfma_f32_16x16x32_bf16(af[mf], bf[nf], acc[mf * 4 + nf], 0, 0, 0);
    __syncthreads();
  }
#pragma unroll
  for (int mf = 0; mf < 4; mf++)
#pragma unroll
    for (int nf = 0; nf < 4; nf++) {
      int gn = bn0 + wc * 64 + nf * 16 + (l & 15);
      int part = gn >> 9, head = (gn >> 6) & 7, d = gn & 63;
      int rbase = bm0 + wr * 64 + mf * 16 + ((l >> 4) << 2);
      int bhead = (rbase >> 13) * 8 + head;
      if (part == 2) {
        union { ushort_t s[4]; unsigned long long u; } p4;
#pragma unroll
        for (int i = 0; i < 4; i++) p4.s[i] = f2bf(acc[mf * 4 + nf][i]);
        *(unsigned long long*)(vT + ((size_t)bhead * 64 + d) * 8192 + (rbase & 8191)) = p4.u;
      } else {
#pragma unroll
        for (int i = 0; i < 4; i++) {
          int gm = rbase + i;
          size_t dst = ((size_t)bhead * 8192 + (gm & 8191)) * 64 + d;
          float val = acc[mf * 4 + nf][i];
          if (part == 0) q[dst] = f2bf(val * 0.125f);
          else k[dst] = f2bf(val);
        }
      }
    }
}

// ------------- MFMA GEMM: gather(outh)[32768,512] @ Woutt^T + x + b -> out --
__global__ __launch_bounds__(256) void gemm_out_mfma(const ushort_t* __restrict__ outh,
                                                     const short* __restrict__ Wt,
                                                     const float* __restrict__ x,
                                                     const float* __restrict__ bo,
                                                     float* __restrict__ out) {
  int bm0 = blockIdx.x * 128, bn0 = blockIdx.y * 128;
  __shared__ __align__(16) short As[128 * 32];
  __shared__ __align__(16) short Bs[128 * 32];
  int t = threadIdx.x, l = t & 63, w = t >> 6;
  int wr = w >> 1, wc = w & 1;
  int arow = w * 32 + (l >> 2);
  int akoff = (l & 3) * 8;
  int gm0 = bm0 + arow, gm1 = gm0 + 16;
  const short* bg = Wt + (size_t)(bn0 + arow) * 512 + akoff;
  short* Adst = As + w * 1024;
  short* Bdst = Bs + w * 1024;
  int lr = l & 15, lk = (l >> 4) * 8;
  const short* Ard = As + (wr * 64 + lr) * 32 + lk;
  const short* Brd = Bs + (wc * 64 + lr) * 32 + lk;
  f32x4 acc[16];
#pragma unroll
  for (int i = 0; i < 16; i++) acc[i] = (f32x4){0.f, 0.f, 0.f, 0.f};
  for (int k0 = 0; k0 < 512; k0 += 32) {
    int kk = k0 + akoff;
    const ushort_t* a0 = outh + ((size_t)((gm0 >> 13) * 8 + (kk >> 6)) * 8192 + (gm0 & 8191)) * 64 + (kk & 63);
    const ushort_t* a1 = outh + ((size_t)((gm1 >> 13) * 8 + (kk >> 6)) * 8192 + (gm1 & 8191)) * 64 + (kk & 63);
    __builtin_amdgcn_global_load_lds(GPTR(a0), LPTR(Adst), 16, 0, 0);
    __builtin_amdgcn_global_load_lds(GPTR(a1), LPTR(Adst + 512), 16, 0, 0);
    __builtin_amdgcn_global_load_lds(GPTR(bg + k0), LPTR(Bdst), 16, 0, 0);
    __builtin_amdgcn_global_load_lds(GPTR(bg + k0 + 16 * 512), LPTR(Bdst + 512), 16, 0, 0);
    __syncthreads();
    short8 af[4], bf[4];
#pragma unroll
    for (int mf = 0; mf < 4; mf++) af[mf] = *(const short8*)(Ard + mf * 512);
#pragma unroll
    for (int nf = 0; nf < 4; nf++) bf[nf] = *(const short8*)(Brd + nf * 512);
#pragma unroll
    for (int mf = 0; mf < 4; mf++)
#pragma unroll
      for (int nf = 0; nf < 4; nf++)
        acc[mf * 4 + nf] = __builtin_amdgcn_mfma_f32_16x16x32_bf16(af[mf], bf[nf], acc[mf * 4 + nf], 0, 0, 0);
    __syncthreads();
  }
#pragma unroll
  for (int mf = 0; mf < 4; mf++)
#pragma unroll
    for (int nf = 0; nf < 4; nf++) {
      int gn = bn0 + wc * 64 + nf * 16 + (l & 15);
      int rbase = bm0 + wr * 64 + mf * 16 + ((l >> 4) << 2);
#pragma unroll
      for (int i = 0; i < 4; i++) {
        int gm = rbase + i;
        size_t o = (size_t)gm * 512 + gn;
        out[o] = x[o] + bo[gn] + acc[mf * 4 + nf][i];
      }
    }
}

// --------- landmarks: mean over 32 rows; fp32 (for sim2) + bf16 copies ------
__global__ void land_kernel(const ushort_t* __restrict__ q, const ushort_t* __restrict__ k,
                            float* __restrict__ qlf, float* __restrict__ klf,
                            ushort_t* __restrict__ qlh, ushort_t* __restrict__ klh) {
  int bh = blockIdx.y, mi = blockIdx.x, d = threadIdx.x;  // 64 threads
  size_t base = ((size_t)bh * 8192 + (size_t)mi * 32) * 64 + d;
  float sq = 0.f, sk = 0.f;
  for (int j = 0; j < 32; j++) {
    sq += bf2f(q[base + (size_t)j * 64]);
    sk += bf2f(k[base + (size_t)j * 64]);
  }
  size_t o = ((size_t)bh * 256 + mi) * 64 + d;
  float aq = sq * (1.f / 32.f), ak = sk * (1.f / 32.f);
  qlf[o] = aq; klf[o] = ak;
  qlh[o] = f2bf(aq); klh[o] = f2bf(ak);
}

// --------- sim2 + softmax -> x (attn2) as hi/lo bf16 [32][256][256] ---------
__global__ __launch_bounds__(256) void sim2_kernel(const float* __restrict__ ql,
                                                   const float* __restrict__ kl,
                                                   ushort_t* __restrict__ xh,
                                                   ushort_t* __restrict__ xl) {
  int bh = blockIdx.y, row = blockIdx.x, t = threadIdx.x;
  __shared__ float qrow[64];
  __shared__ float red[256];
  if (t < 64) qrow[t] = ql[((size_t)bh * 256 + row) * 64 + t];
  __syncthreads();
  const float* kr = kl + ((size_t)bh * 256 + t) * 64;
  float s = 0.f;
#pragma unroll
  for (int kd = 0; kd < 64; kd++) s = fmaf(qrow[kd], kr[kd], s);
  red[t] = s; __syncthreads();
  for (int off = 128; off > 0; off >>= 1) { if (t < off) red[t] = fmaxf(red[t], red[t + off]); __syncthreads(); }
  float mx = red[0]; __syncthreads();
  float pv = __expf(s - mx);
  red[t] = pv; __syncthreads();
  for (int off = 128; off > 0; off >>= 1) { if (t < off) red[t] += red[t + off]; __syncthreads(); }
  float pn = pv / red[0];
  size_t idx = ((size_t)bh << 16) + (size_t)row * 256 + t;
  ushort_t hi = f2bf(pn);
  xh[idx] = hi;
  xl[idx] = f2bf(pn - bf2f(hi));
}

// ------------- pinv init: abs row/col sums from hi/lo ----------------------
__global__ __launch_bounds__(256) void abssum_kernel(const ushort_t* __restrict__ xh,
                                                     const ushort_t* __restrict__ xl,
                                                     float* __restrict__ rowsum,
                                                     float* __restrict__ colsum) {
  int bh = blockIdx.x, t = threadIdx.x;
  size_t off = (size_t)bh << 16;
  float s = 0.f;
  for (int c = 0; c < 256; c++) {
    size_t i = off + (size_t)t * 256 + c;
    s += fabsf(bf2f(xh[i]) + bf2f(xl[i]));
  }
  rowsum[bh * 256 + t] = s;
  float s2 = 0.f;
  for (int r = 0; r < 256; r++) {
    size_t i = off + (size_t)r * 256 + t;
    s2 += fabsf(bf2f(xh[i]) + bf2f(xl[i]));
  }
  colsum[bh * 256 + t] = s2;
}

__global__ __launch_bounds__(256) void pinv_scale_kernel(const float* __restrict__ rowsum,
                                                         const float* __restrict__ colsum,
                                                         float* __restrict__ scl) {
  int t = threadIdx.x;
  float m1 = 0.f, m2 = 0.f;
  for (int i = t; i < 8192; i += 256) { m1 = fmaxf(m1, rowsum[i]); m2 = fmaxf(m2, colsum[i]); }
  __shared__ float r1[256], r2[256];
  r1[t] = m1; r2[t] = m2; __syncthreads();
  for (int off = 128; off > 0; off >>= 1) {
    if (t < off) { r1[t] = fmaxf(r1[t], r1[t + off]); r2[t] = fmaxf(r2[t], r2[t + off]); }
    __syncthreads();
  }
  if (t == 0) scl[0] = 1.f / (r1[0] * r2[0]);
}

// ------------- z0 = x^T*s (row hi/lo) and z0^T = x*s (hi/lo) ---------------
__global__ __launch_bounds__(256) void zinit_kernel(const ushort_t* __restrict__ xh,
                                                    const ushort_t* __restrict__ xl,
                                                    const float* __restrict__ scl,
                                                    ushort_t* __restrict__ zrh,
                                                    ushort_t* __restrict__ zrl,
                                                    ushort_t* __restrict__ zth,
                                                    ushort_t* __restrict__ ztl) {
  int bh = blockIdx.y, i = blockIdx.x, j = threadIdx.x;
  size_t off = (size_t)bh << 16;
  float s = scl[0];
  size_t src1 = off + (size_t)j * 256 + i;
  float v1 = (bf2f(xh[src1]) + bf2f(xl[src1])) * s;
  size_t dst = off + (size_t)i * 256 + j;
  ushort_t h1 = f2bf(v1);
  zrh[dst] = h1; zrl[dst] = f2bf(v1 - bf2f(h1));
  size_t src2 = off + (size_t)i * 256 + j;
  float v2 = (bf2f(xh[src2]) + bf2f(xl[src2])) * s;
  ushort_t h2 = f2bf(v2);
  zth[dst] = h2; ztl[dst] = f2bf(v2 - bf2f(h2));
}

// ------- NS split-precision MFMA GEMM on [32][256][256] hi/lo bf16 ---------
// C = A @ B, A stored as rows (hi/lo); B stored as B^T rows (hi/lo).
// MODE 0: E=acc;          write C rows + C^T     (A = x@z)
// MODE 1: E=acc-7Ex+15I;  write C^T only         (D = A@A-7A+15I)
// MODE 2: E=13I-acc;      write C^T only         (F = 13I-A@D)
// MODE 3: E=0.25*acc;     write C rows + C^T     (z' = 0.25*z@F)
// 2-phase pipelined staging (issue next stage before MFMA), LDS-bounce epilogue.
template<int MODE>
__global__ __launch_bounds__(256) void bmm_ns(
    const ushort_t* __restrict__ Agh, const ushort_t* __restrict__ Agl,
    const ushort_t* __restrict__ Bgh, const ushort_t* __restrict__ Bgl,
    const ushort_t* __restrict__ Exh, const ushort_t* __restrict__ Exl,
    ushort_t* __restrict__ C1h, ushort_t* __restrict__ C1l,
    ushort_t* __restrict__ C2h, ushort_t* __restrict__ C2l) {
  __shared__ __align__(16) char smem[65536];   // [Ah|Bh|Al|Bl] x 2 bufs x 8KB
  char* AhB = smem;
  char* BhB = smem + 16384;
  char* AlB = smem + 32768;
  char* BlB = smem + 49152;

  int t = threadIdx.x, l = t & 63, w = t >> 6, h = l >> 5;
  int tile = blockIdx.x, bh = blockIdx.y;
  int tr = (tile >> 2) << 6, tc = (tile & 3) << 6;
  size_t off = (size_t)bh << 16;

  // staging chunk assignment (pre-swizzled global source, linear LDS dst)
  int id0 = w * 64 + l, id1 = id0 + 256;
  int r0 = id0 >> 3, cs0 = (id0 & 7) ^ (r0 & 7);
  int r1 = id1 >> 3, cs1 = (id1 & 7) ^ (r1 & 7);

  auto stage = [&](int s, int d) {
    int k0 = s << 6;
    int db = d * 8192;
    const ushort_t* a0 = Agh + off + (size_t)(tr + r0) * 256 + k0 + cs0 * 8;
    const ushort_t* a1 = Agh + off + (size_t)(tr + r1) * 256 + k0 + cs1 * 8;
    const ushort_t* b0 = Bgh + off + (size_t)(tc + r0) * 256 + k0 + cs0 * 8;
    const ushort_t* b1 = Bgh + off + (size_t)(tc + r1) * 256 + k0 + cs1 * 8;
    __builtin_amdgcn_global_load_lds(GPTR(a0), LPTR(AhB + db + w * 1024), 16, 0, 0);
    __builtin_amdgcn_global_load_lds(GPTR(a1), LPTR(AhB + db + w * 1024 + 4096), 16, 0, 0);
    __builtin_amdgcn_global_load_lds(GPTR(b0), LPTR(BhB + db + w * 1024), 16, 0, 0);
    __builtin_amdgcn_global_load_lds(GPTR(b1), LPTR(BhB + db + w * 1024 + 4096), 16, 0, 0);
    const ushort_t* a2 = Agl + off + (size_t)(tr + r0) * 256 + k0 + cs0 * 8;
    const ushort_t* a3 = Agl + off + (size_t)(tr + r1) * 256 + k0 + cs1 * 8;
    const ushort_t* b2 = Bgl + off + (size_t)(tc + r0) * 256 + k0 + cs0 * 8;
    const ushort_t* b3 = Bgl + off + (size_t)(tc + r1) * 256 + k0 + cs1 * 8;
    __builtin_amdgcn_global_load_lds(GPTR(a2), LPTR(AlB + db + w * 1024), 16, 0, 0);
    __builtin_amdgcn_global_load_lds(GPTR(a3), LPTR(AlB + db + w * 1024 + 4096), 16, 0, 0);
    __builtin_amdgcn_global_load_lds(GPTR(b2), LPTR(BlB + db + w * 1024), 16, 0, 0);
    __builtin_amdgcn_global_load_lds(GPTR(b3), LPTR(BlB + db + w * 1024 + 4096), 16, 0, 0);
  };

  f32x16 acc;
#pragma unroll
  for (int i = 0; i < 16; i++) acc[i] = 0.f;

  int rA = ((w >> 1) << 5) + (l & 31);
  int rB = ((w & 1) << 5) + (l & 31);
  int baA = rA << 7, baB = rB << 7;   // byte row bases (128B rows)

  stage(0, 0);
  __syncthreads();
  for (int s = 0; s < 4; s++) {
    if (s < 3) stage(s + 1, (s + 1) & 1);
    int db = (s & 1) * 8192;
#pragma unroll
    for (int kk = 0; kk < 4; kk++) {
      int swA = (((kk << 1) + h) ^ (rA & 7)) << 4;
      int swB = (((kk << 1) + h) ^ (rB & 7)) << 4;
      short8 afh = *(const short8*)(AhB + db + baA + swA);
      short8 bfh = *(const short8*)(BhB + db + baB + swB);
      short8 afl = *(const short8*)(AlB + db + baA + swA);
      short8 bfl = *(const short8*)(BlB + db + baB + swB);
      acc = __builtin_amdgcn_mfma_f32_32x32x16_bf16(afh, bfh, acc, 0, 0, 0);
      acc = __builtin_amdgcn_mfma_f32_32x32x16_bf16(afh, bfl, acc, 0, 0, 0);
      acc = __builtin_amdgcn_mfma_f32_32x32x16_bf16(afl, bfh, acc, 0, 0, 0);
    }
    __syncthreads();   // drains prefetch (vmcnt) + releases buf for next overwrite
  }

  // ---------------- epilogue: compute hi/lo, LDS-bounce, coalesced stores ---
  int qr = tr + ((w >> 1) << 5);
  int nloc = ((w & 1) << 5) + (l & 31);
  int gn = tc + nloc;
  ushort_t his[16], los[16];
  int ms[16];
#pragma unroll
  for (int reg = 0; reg < 16; reg++) {
    int m = (reg & 3) + ((reg >> 2) << 3) + (h << 2);
    int gm = qr + m;
    float e = acc[reg];
    if (MODE == 1) {
      size_t ei = off + (size_t)gm * 256 + gn;
      e = e - 7.f * (bf2f(Exh[ei]) + bf2f(Exl[ei])) + (gm == gn ? 15.f : 0.f);
    } else if (MODE == 2) {
      e = (gm == gn ? 13.f : 0.f) - e;
    } else if (MODE == 3) {
      e *= 0.25f;
    }
    his[reg] = f2bf(e);
    los[reg] = f2bf(e - bf2f(his[reg]));
    ms[reg] = ((w >> 1) << 5) + m;   // m_local in [0,64)
  }
  ushort_t* Whi = (ushort_t*)smem;           // 64 x 72 ushorts
  ushort_t* Wlo = ((ushort_t*)smem) + 4608;
  // pass 1: transposed tile LDS_T[n][m] -> C^T rows
#pragma unroll
  for (int reg = 0; reg < 16; reg++) {
    Whi[nloc * 72 + ms[reg]] = his[reg];
    Wlo[nloc * 72 + ms[reg]] = los[reg];
  }
  __syncthreads();
  {
    int rr = t >> 2, seg = (t & 3) << 4;
    uint4 h0 = *(const uint4*)(Whi + rr * 72 + seg);
    uint4 h1 = *(const uint4*)(Whi + rr * 72 + seg + 8);
    uint4 l0 = *(const uint4*)(Wlo + rr * 72 + seg);
    uint4 l1 = *(const uint4*)(Wlo + rr * 72 + seg + 8);
    size_t d2 = off + (size_t)(tc + rr) * 256 + tr + seg;
    *(uint4*)(C2h + d2) = h0; *(uint4*)(C2h + d2 + 8) = h1;
    *(uint4*)(C2l + d2) = l0; *(uint4*)(C2l + d2 + 8) = l1;
  }
  if (MODE == 0 || MODE == 3) {
    __syncthreads();
    // pass 2: natural tile LDS[m][n] -> C rows
#pragma unroll
    for (int reg = 0; reg < 16; reg++) {
      Whi[ms[reg] * 72 + nloc] = his[reg];
      Wlo[ms[reg] * 72 + nloc] = los[reg];
    }
    __syncthreads();
    int rr = t >> 2, seg = (t & 3) << 4;
    uint4 h0 = *(const uint4*)(Whi + rr * 72 + seg);
    uint4 h1 = *(const uint4*)(Whi + rr * 72 + seg + 8);
    uint4 l0 = *(const uint4*)(Wlo + rr * 72 + seg);
    uint4 l1 = *(const uint4*)(Wlo + rr * 72 + seg + 8);
    size_t d1 = off + (size_t)(tr + rr) * 256 + tc + seg;
    *(uint4*)(C1h + d1) = h0; *(uint4*)(C1h + d1 + 8) = h1;
    *(uint4*)(C1l + d1) = l0; *(uint4*)(C1l + d1 + 8) = l1;
  }
}

// ------------- MFMA flash: out = softmax(qsrc @ ksrc^T) @ V ----------------
__global__ __launch_bounds__(256) void flash_mfma(
    const ushort_t* __restrict__ qsrc, const ushort_t* __restrict__ ksrc,
    const ushort_t* __restrict__ vts, ushort_t* __restrict__ outb,
    float* __restrict__ pOT, float* __restrict__ pM, float* __restrict__ pL,
    int nq, int nkv, int vt_stride, int nsplit, int write_partial) {
  __shared__ __align__(16) char smem[64 * 132 * 4];
  ushort_t* Ks = (ushort_t*)smem;
  ushort_t* Vs = (ushort_t*)(smem + 8192);
  float* Ot = (float*)smem;

  int t = threadIdx.x, l = t & 63, w = t >> 6, h = l >> 5, ql = l & 31;
  int qtile = blockIdx.x, sp = blockIdx.y, bh = blockIdx.z;
  int chunk = nkv / nsplit;
  int kvbase = sp * chunk;
  int qg = qtile * 128 + w * 32 + ql;

  const ushort_t* qp = qsrc + ((size_t)bh * nq + qg) * 64;
  short8 qf[4];
#pragma unroll
  for (int kk = 0; kk < 4; kk++) qf[kk] = *(const short8*)(qp + kk * 16 + h * 8);

  f32x16 acc0, acc1;
#pragma unroll
  for (int i = 0; i < 16; i++) { acc0[i] = 0.f; acc1[i] = 0.f; }

  int c0 = w * 64 + l, c1 = c0 + 256;
  int r0 = c0 >> 3, s0 = ((c0 & 7) ^ (r0 & 7)) << 3;
  int r1 = c1 >> 3, s1 = ((c1 & 7) ^ (r1 & 7)) << 3;
  const ushort_t* kb = ksrc + (size_t)bh * nkv * 64;
  const ushort_t* vb = vts + (size_t)bh * 64 * vt_stride;

  float mrun = -1e30f, lrun = 0.f;
  int ntiles = chunk >> 6;
  for (int it = 0; it < ntiles; it++) {
    int kvt = kvbase + it * 64;
    __syncthreads();
    __builtin_amdgcn_global_load_lds(GPTR(kb + (size_t)(kvt + r0) * 64 + s0), LPTR(Ks + w * 512), 16, 0, 0);
    __builtin_amdgcn_global_load_lds(GPTR(kb + (size_t)(kvt + r1) * 64 + s1), LPTR(Ks + 2048 + w * 512), 16, 0, 0);
    __builtin_amdgcn_global_load_lds(GPTR(vb + (size_t)r0 * vt_stride + kvt + s0), LPTR(Vs + w * 512), 16, 0, 0);
    __builtin_amdgcn_global_load_lds(GPTR(vb + (size_t)r1 * vt_stride + kvt + s1), LPTR(Vs + 2048 + w * 512), 16, 0, 0);
    __syncthreads();

    f32x16 st0, st1;
#pragma unroll
    for (int i = 0; i < 16; i++) { st0[i] = 0.f; st1[i] = 0.f; }
#pragma unroll
    for (int kk = 0; kk < 4; kk++) {
      int ch = kk * 2 + h;
      short8 kf0 = *(const short8*)(Ks + ql * 64 + ((ch ^ (ql & 7)) << 3));
      short8 kf1 = *(const short8*)(Ks + (32 + ql) * 64 + ((ch ^ (ql & 7)) << 3));
      st0 = __builtin_amdgcn_mfma_f32_32x32x16_bf16(kf0, qf[kk], st0, 0, 0, 0);
      st1 = __builtin_amdgcn_mfma_f32_32x32x16_bf16(kf1, qf[kk], st1, 0, 0, 0);
    }

    float tm = -1e30f;
#pragma unroll
    for (int r2 = 0; r2 < 16; r2++) { tm = fmaxf(tm, st0[r2]); tm = fmaxf(tm, st1[r2]); }
    tm = fmaxf(tm, __shfl_xor(tm, 32));
    float mnew = fmaxf(mrun, tm);
    float scal = __expf(mrun - mnew);
    float tsum = 0.f;
#pragma unroll
    for (int r2 = 0; r2 < 16; r2++) {
      float p0 = __expf(st0[r2] - mnew); st0[r2] = p0; tsum += p0;
      float p1 = __expf(st1[r2] - mnew); st1[r2] = p1; tsum += p1;
    }
    tsum += __shfl_xor(tsum, 32);
    lrun = lrun * scal + tsum;
    mrun = mnew;
#pragma unroll
    for (int r2 = 0; r2 < 16; r2++) { acc0[r2] *= scal; acc1[r2] *= scal; }

#pragma unroll
    for (int nf = 0; nf < 2; nf++) {
      f32x16 stv = (nf == 0) ? st0 : st1;
      unsigned int pk[8], sw[8];
#pragma unroll
      for (int g2 = 0; g2 < 4; g2++) {
        pk[g2 * 2]     = (unsigned int)f2bf(stv[g2 * 4])     | ((unsigned int)f2bf(stv[g2 * 4 + 1]) << 16);
        pk[g2 * 2 + 1] = (unsigned int)f2bf(stv[g2 * 4 + 2]) | ((unsigned int)f2bf(stv[g2 * 4 + 3]) << 16);
      }
#pragma unroll
      for (int i2 = 0; i2 < 8; i2++) sw[i2] = (unsigned int)__shfl_xor((int)pk[i2], 32);
      union { unsigned int u[4]; short8 s; } bfr0, bfr1;
      if (h == 0) {
        bfr0.u[0] = pk[0]; bfr0.u[1] = pk[1]; bfr0.u[2] = sw[0]; bfr0.u[3] = sw[1];
        bfr1.u[0] = pk[4]; bfr1.u[1] = pk[5]; bfr1.u[2] = sw[4]; bfr1.u[3] = sw[5];
      } else {
        bfr0.u[0] = sw[2]; bfr0.u[1] = sw[3]; bfr0.u[2] = pk[2]; bfr0.u[3] = pk[3];
        bfr1.u[0] = sw[6]; bfr1.u[1] = sw[7]; bfr1.u[2] = pk[6]; bfr1.u[3] = pk[7];
      }
#pragma unroll
      for (int ks2 = 0; ks2 < 2; ks2++) {
        int ch2 = nf * 4 + ks2 * 2 + h;
        short8 vf0 = *(const short8*)(Vs + ql * 64 + ((ch2 ^ (ql & 7)) << 3));
        short8 vf1 = *(const short8*)(Vs + (32 + ql) * 64 + ((ch2 ^ (ql & 7)) << 3));
        short8 pf = ks2 ? bfr1.s : bfr0.s;
        acc0 = __builtin_amdgcn_mfma_f32_32x32x16_bf16(vf0, pf, acc0, 0, 0, 0);
        acc1 = __builtin_amdgcn_mfma_f32_32x32x16_bf16(vf1, pf, acc1, 0, 0, 0);
      }
    }
  }

  if (write_partial) {
    size_t ob = (size_t)bh * nsplit + sp;
#pragma unroll
    for (int r2 = 0; r2 < 16; r2++) {
      int row = (r2 & 3) + 8 * (r2 >> 2) + 4 * h;
      pOT[(ob * 64 + row) * nq + qg] = acc0[r2];
      pOT[(ob * 64 + 32 + row) * nq + qg] = acc1[r2];
    }
    if (h == 0) { pM[ob * nq + qg] = mrun; pL[ob * nq + qg] = lrun; }
  } else {
    float inv = 1.f / lrun;
    __syncthreads();
#pragma unroll
    for (int r2 = 0; r2 < 16; r2++) {
      int row = (r2 & 3) + 8 * (r2 >> 2) + 4 * h;
      Ot[row * 132 + w * 32 + ql] = acc0[r2] * inv;
      Ot[(32 + row) * 132 + w * 32 + ql] = acc1[r2] * inv;
    }
    __syncthreads();
    int qrow = t >> 1, half = t & 1;
    float vloc[32];
#pragma unroll
    for (int j = 0; j < 32; j++) vloc[j] = Ot[(half * 32 + j) * 132 + qrow];
    ushort_t* op = outb + ((size_t)bh * nq + qtile * 128 + qrow) * 64 + half * 32;
#pragma unroll
    for (int seg = 0; seg < 4; seg++) {
      union { ushort_t s[8]; uint4 u; } o8;
#pragma unroll
      for (int j = 0; j < 8; j++) o8.s[j] = f2bf(vloc[seg * 8 + j]);
      *(uint4*)(op + seg * 8) = o8.u;
    }
  }
}

// ------------- combine split-KV partials -> T bf16 [bh][256][64] -----------
#define NSPLIT 8
__global__ __launch_bounds__(256) void flash_combine(const float* __restrict__ pOT,
                                                     const float* __restrict__ pM,
                                                     const float* __restrict__ pL,
                                                     ushort_t* __restrict__ T, int nq) {
  int bh = blockIdx.x, qq = threadIdx.x;
  float ms[NSPLIT], ww[NSPLIT];
  float M = -1e30f;
#pragma unroll
  for (int s = 0; s < NSPLIT; s++) {
    ms[s] = pM[((size_t)bh * NSPLIT + s) * nq + qq];
    M = fmaxf(M, ms[s]);
  }
  float L = 0.f;
#pragma unroll
  for (int s = 0; s < NSPLIT; s++) {
    ww[s] = __expf(ms[s] - M);
    L += ww[s] * pL[((size_t)bh * NSPLIT + s) * nq + qq];
  }
  float invL = 1.f / L;
  ushort_t* tp = T + ((size_t)bh * nq + qq) * 64;
  for (int d0 = 0; d0 < 64; d0 += 8) {
    union { ushort_t s[8]; uint4 u; } o8;
#pragma unroll
    for (int j = 0; j < 8; j++) {
      int d = d0 + j;
      float o = 0.f;
#pragma unroll
      for (int s = 0; s < NSPLIT; s++)
        o += ww[s] * pOT[(((size_t)bh * NSPLIT + s) * 64 + d) * nq + qq];
      o8.s[j] = f2bf(o * invL);
    }
    *(uint4*)(tp + d0) = o8.u;
  }
}

// ------------- U^T = (z @ T)^T : UT[bh][64][256], z from hi/lo --------------
// grid (8, 32): block covers 32 z-rows x 64 d. T tile staged in LDS.
__global__ __launch_bounds__(256) void zu_kernel(const ushort_t* __restrict__ zh,
                                                 const ushort_t* __restrict__ zl,
                                                 const ushort_t* __restrict__ T,
                                                 ushort_t* __restrict__ UT) {
  __shared__ __align__(16) ushort_t Ts[16384];   // [256][64]
  __shared__ __align__(16) ushort_t Ub[64 * 40]; // bounce [d][r] pad 40
  int bh = blockIdx.y, r0 = blockIdx.x * 32, t = threadIdx.x;
  {
    const uint4* src = (const uint4*)(T + ((size_t)bh << 14));
    uint4* dst = (uint4*)Ts;
    for (int i = t; i < 2048; i += 256) dst[i] = src[i];
  }
  __syncthreads();
  int rloc = t >> 3, dseg = (t & 7) << 3;
  size_t zoff = ((size_t)bh << 16) + (size_t)(r0 + rloc) * 256;
  float acc[8];
#pragma unroll
  for (int j = 0; j < 8; j++) acc[j] = 0.f;
  for (int c0 = 0; c0 < 256; c0 += 8) {
    uint4 zhv = *(const uint4*)(zh + zoff + c0);
    uint4 zlv = *(const uint4*)(zl + zoff + c0);
    const ushort_t* z8h = (const ushort_t*)&zhv;
    const ushort_t* z8l = (const ushort_t*)&zlv;
#pragma unroll
    for (int cc = 0; cc < 8; cc++) {
      float zv = bf2f(z8h[cc]) + bf2f(z8l[cc]);
      short8 tv = *(const short8*)(Ts + (c0 + cc) * 64 + dseg);
#pragma unroll
      for (int j = 0; j < 8; j++) acc[j] = fmaf(zv, bf2f((ushort_t)tv[j]), acc[j]);
    }
  }
#pragma unroll
  for (int j = 0; j < 8; j++) Ub[(dseg + j) * 40 + rloc] = f2bf(acc[j]);
  __syncthreads();
  int d = t >> 2, rseg = (t & 3) << 3;
  uint4 v = *(const uint4*)(Ub + d * 40 + rseg);
  *(uint4*)(UT + ((size_t)bh * 64 + d) * 256 + r0 + rseg) = v;
}

// ------------- depthwise residual conv over n (k=33) from vT, += outh ------
__global__ __launch_bounds__(256) void conv_vt(const ushort_t* __restrict__ vT,
                                               const float* __restrict__ wcv,
                                               ushort_t* __restrict__ outh) {
  __shared__ float vs[64][165];
  int bh = blockIdx.y, n0 = blockIdx.x * 128, t = threadIdx.x;
  int hh = bh & 7;
  {
    int r = t >> 2, part = t & 3;
    const ushort_t* src = vT + ((size_t)bh * 64 + r) * 8192;
#pragma unroll
    for (int j = 0; j < 5; j++) {
      int col = part * 40 + j * 8;
      int gn = n0 - 16 + col;
      float tmp[8];
      if (gn >= 0 && gn + 7 < 8192) {
        uint4 u = *(const uint4*)(src + gn);
        const ushort_t* us = (const ushort_t*)&u;
#pragma unroll
        for (int e = 0; e < 8; e++) tmp[e] = bf2f(us[e]);
      } else {
#pragma unroll
        for (int e = 0; e < 8; e++) {
          int g2 = gn + e;
          tmp[e] = (g2 >= 0 && g2 < 8192) ? bf2f(src[g2]) : 0.f;
        }
      }
#pragma unroll
      for (int e = 0; e < 8; e++) vs[r][col + e] = tmp[e];
    }
  }
  __syncthreads();
  int d = t & 63, ng = t >> 6;
  float win[64];
#pragma unroll
  for (int j = 0; j < 64; j++) win[j] = vs[d][ng * 32 + j];
  float o[32];
#pragma unroll
  for (int i = 0; i < 32; i++) o[i] = 0.f;
#pragma unroll
  for (int kk = 0; kk < 33; kk++) {
    float wv = wcv[hh * 33 + kk];
#pragma unroll
    for (int i = 0; i < 32; i++) o[i] = fmaf(wv, win[i + kk], o[i]);
  }
  ushort_t* op = outh + ((size_t)bh * 8192 + n0 + ng * 32) * 64 + d;
#pragma unroll
  for (int i = 0; i < 32; i++) {
    size_t oo = (size_t)i * 64;
    op[oo] = f2bf(bf2f(op[oo]) + o[i]);
  }
}

extern "C" void kernel_launch(void* const* d_in, const int* in_sizes, int n_in,
                              void* d_out, int out_size, void* d_ws, size_t ws_size,
                              hipStream_t stream) {
  (void)in_sizes; (void)n_in; (void)out_size; (void)ws_size;
  const float* x     = (const float*)d_in[0];
  const float* g     = (const float*)d_in[1];
  const float* be    = (const float*)d_in[2];
  const float* wqkv  = (const float*)d_in[3];
  const float* wout  = (const float*)d_in[4];
  const float* bout  = (const float*)d_in[5];
  const float* convw = (const float*)d_in[6];
  float* out = (float*)d_out;

  char* base = (char*)d_ws;
  size_t off = 0;
  auto alloc = [&](size_t bytes) -> void* {
    void* r = base + off; off = (off + bytes + 255) & ~(size_t)255; return r;
  };
  const size_t NBH = (size_t)32 * 8192 * 64;
  const size_t M2 = (size_t)32 * 256 * 256 * 2;  // one [32][256][256] bf16 = 4 MB
  ushort_t* q     = (ushort_t*)alloc(NBH * 2);
  ushort_t* k     = (ushort_t*)alloc(NBH * 2);
  ushort_t* vT    = (ushort_t*)alloc(NBH * 2);
  ushort_t* outh  = (ushort_t*)alloc(NBH * 2);
  float*    qlf   = (float*)alloc((size_t)32 * 256 * 64 * 4);
  float*    klf   = (float*)alloc((size_t)32 * 256 * 64 * 4);
  ushort_t* qlh   = (ushort_t*)alloc((size_t)32 * 256 * 64 * 2);
  ushort_t* klh   = (ushort_t*)alloc((size_t)32 * 256 * 64 * 2);
  ushort_t* xh    = (ushort_t*)alloc(M2);
  ushort_t* xl    = (ushort_t*)alloc(M2);
  ushort_t* zArh  = (ushort_t*)alloc(M2);
  ushort_t* zArl  = (ushort_t*)alloc(M2);
  ushort_t* zAth  = (ushort_t*)alloc(M2);
  ushort_t* zAtl  = (ushort_t*)alloc(M2);
  ushort_t* zBrh  = (ushort_t*)alloc(M2);
  ushort_t* zBrl  = (ushort_t*)alloc(M2);
  ushort_t* zBth  = (ushort_t*)alloc(M2);
  ushort_t* zBtl  = (ushort_t*)alloc(M2);
  ushort_t* ARh   = (ushort_t*)alloc(M2);
  ushort_t* ARl   = (ushort_t*)alloc(M2);
  ushort_t* ATh   = (ushort_t*)alloc(M2);
  ushort_t* ATl   = (ushort_t*)alloc(M2);
  ushort_t* DTh   = (ushort_t*)alloc(M2);
  ushort_t* DTl   = (ushort_t*)alloc(M2);
  ushort_t* FTh   = (ushort_t*)alloc(M2);
  ushort_t* FTl   = (ushort_t*)alloc(M2);
  float*    rowsum = (float*)alloc(8192 * 4);
  float*    colsum = (float*)alloc(8192 * 4);
  float*    scl   = (float*)alloc(64);
  ushort_t* T     = (ushort_t*)alloc((size_t)32 * 256 * 64 * 2);
  ushort_t* UT    = (ushort_t*)alloc((size_t)32 * 64 * 256 * 2);
  ushort_t* Wqkvt = (ushort_t*)alloc((size_t)1536 * 512 * 2);
  ushort_t* Woutt = (ushort_t*)alloc((size_t)512 * 512 * 2);
  // Aliases: LN output Abf (33.55 MB) spans xh..zBtl (10 x 4.19 MB, written
  // only later). Flash partials -> ARh..ATl (pOT 16.78 MB) and DTh (pM/pL),
  // all dead after the pinv loop.
  short* Abf = (short*)xh;
  float* pOT = (float*)ARh;
  float* pM  = (float*)DTh;
  float* pL  = (float*)DTh + 65536;

  ln_bf16<<<32768, 256, 0, stream>>>(x, g, be, (ushort_t*)Abf);
  wtrans<<<dim3(8, 24), 256, 0, stream>>>(wqkv, Wqkvt, 512, 1536);
  wtrans<<<dim3(8, 8), 256, 0, stream>>>(wout, Woutt, 512, 512);
  gemm_qkv_mfma<<<dim3(256, 12), 256, 0, stream>>>(Abf, (const short*)Wqkvt, q, k, vT);
  land_kernel<<<dim3(256, 32), 64, 0, stream>>>(q, k, qlf, klf, qlh, klh);
  sim2_kernel<<<dim3(256, 32), 256, 0, stream>>>(qlf, klf, xh, xl);
  abssum_kernel<<<32, 256, 0, stream>>>(xh, xl, rowsum, colsum);
  pinv_scale_kernel<<<1, 256, 0, stream>>>(rowsum, colsum, scl);
  zinit_kernel<<<dim3(256, 32), 256, 0, stream>>>(xh, xl, scl, zArh, zArl, zAth, zAtl);

  ushort_t *zrh = zArh, *zrl = zArl, *zth = zAth, *ztl = zAtl;
  ushort_t *nrh = zBrh, *nrl = zBrl, *nth = zBth, *ntl = zBtl;
  dim3 nsgrid(16, 32);
  for (int it = 0; it < 6; it++) {
    bmm_ns<0><<<nsgrid, 256, 0, stream>>>(xh, xl, zth, ztl, xh, xl, ARh, ARl, ATh, ATl);
    bmm_ns<1><<<nsgrid, 256, 0, stream>>>(ARh, ARl, ATh, ATl, ARh, ARl, xh, xl, DTh, DTl);
    bmm_ns<2><<<nsgrid, 256, 0, stream>>>(ARh, ARl, DTh, DTl, xh, xl, xh, xl, FTh, FTl);
    bmm_ns<3><<<nsgrid, 256, 0, stream>>>(zrh, zrl, FTh, FTl, xh, xl, nrh, nrl, nth, ntl);
    std::swap(zrh, nrh); std::swap(zrl, nrl);
    std::swap(zth, nth); std::swap(ztl, ntl);
  }
  // after 6 swaps, final z rows = zArh/zArl (= zrh/zrl). A/D/F/x now dead.

  // T = softmax(q_land @ k^T) @ v   (split-KV 8, partials f32)
  flash_mfma<<<dim3(2, 8, 32), 256, 0, stream>>>(qlh, k, vT, T, pOT, pM, pL,
                                                 256, 8192, 8192, 8, 1);
  flash_combine<<<32, 256, 0, stream>>>(pOT, pM, pL, T, 256);
  // UT = (z @ T)^T
  zu_kernel<<<dim3(8, 32), 256, 0, stream>>>(zrh, zrl, T, UT);
  // outh = softmax(q @ k_land^T) @ U
  flash_mfma<<<dim3(64, 1, 32), 256, 0, stream>>>(q, klh, UT, outh, pOT, pM, pL,
                                                  8192, 256, 256, 1, 0);
  // outh += depthwise conv residual of v
  conv_vt<<<dim3(64, 32), 256, 0, stream>>>(vT, convw, outh);
  // d_out = x + concat_heads(outh) @ w_out + b_out
  gemm_out_mfma<<<dim3(256, 4), 256, 0, stream>>>(outh, (const short*)Woutt, x, bout, out);
}